// Round 8
// baseline (186.023 us; speedup 1.0000x reference)
//
#include <hip/hip_runtime.h>
#include <hip/hip_bf16.h>

#define H_DIM 768
#define NHEAD 12
#define HDIM  64
#define S_LEN 2048
#define B_SZ  2
#define M_TOT (B_SZ * S_LEN)   // 4096
#define NQKV  (3 * H_DIM)      // 2304
#define LN_EPS 1e-5f
#define SM_C   0.1803368801f   // 0.125 * log2(e)

typedef __attribute__((ext_vector_type(8))) short bf16x8;
typedef __attribute__((ext_vector_type(4))) float f32x4;

static __device__ inline ushort f2bf(float x) {
    __hip_bfloat16 h = __float2bfloat16(x);
    ushort u;
    __builtin_memcpy(&u, &h, 2);
    return u;
}
static __device__ inline float bf2f(ushort u) {
    unsigned int v = ((unsigned int)u) << 16;
    float f;
    __builtin_memcpy(&f, &v, 4);
    return f;
}

#define GLDS16(g, l) __builtin_amdgcn_global_load_lds( \
    (const __attribute__((address_space(1))) void*)(g), \
    (__attribute__((address_space(3))) void*)(l), 16, 0, 0)

// ---------------- converters ----------------------------------------------
__global__ __launch_bounds__(256)
void convert_x(const float* __restrict__ src, ushort* __restrict__ dst)
{
    const int i = (blockIdx.x * 256 + threadIdx.x) * 4;
    f32x4 v = *(const f32x4*)(src + i);
    ushort4 o;
    o.x = f2bf(v[0]); o.y = f2bf(v[1]); o.z = f2bf(v[2]); o.w = f2bf(v[3]);
    *(ushort4*)(dst + i) = o;
}

__global__ __launch_bounds__(256)
void concat_bias(const float* __restrict__ bq, const float* __restrict__ bk,
                 const float* __restrict__ bv, float* __restrict__ dst)
{
    const int t = blockIdx.x * 256 + threadIdx.x;
    if (t < NQKV) {
        float v = (t < 768) ? bq[t] : (t < 1536) ? bk[t - 768] : bv[t - 1536];
        dst[t] = v;
    }
}

// W[k][n] f32 -> Wt[n][k] bf16 (z=0..2 into Wcat rows z*768.., z=3 into Wot)
__global__ __launch_bounds__(256)
void convert_w(const float* __restrict__ Wq, const float* __restrict__ Wk,
               const float* __restrict__ Wv, const float* __restrict__ Wo,
               ushort* __restrict__ Wcat, ushort* __restrict__ Wot)
{
    const int k0 = blockIdx.x * 64;
    const int n0 = blockIdx.y * 64;
    const int z  = blockIdx.z;
    const float* W = (z == 0) ? Wq : (z == 1) ? Wk : (z == 2) ? Wv : Wo;
    __shared__ ushort T[64][65];
    const int t = threadIdx.x;
    const int r = t >> 2, c0 = (t & 3) * 16;
    const float* src = W + (size_t)(k0 + r) * H_DIM + n0 + c0;
    #pragma unroll
    for (int j = 0; j < 16; j += 4) {
        f32x4 v = *(const f32x4*)(src + j);
        #pragma unroll
        for (int jj = 0; jj < 4; ++jj) T[r][c0 + j + jj] = f2bf(v[jj]);
    }
    __syncthreads();
    bf16x8 o0, o1;
    #pragma unroll
    for (int j = 0; j < 8; ++j) {
        o0[j] = (short)T[c0 + j][r];
        o1[j] = (short)T[c0 + 8 + j][r];
    }
    ushort* dst = (z < 3)
        ? Wcat + (size_t)(z * 768 + n0 + r) * H_DIM + k0 + c0
        : Wot  + (size_t)(n0 + r) * H_DIM + k0 + c0;
    *(bf16x8*)dst       = o0;
    *(bf16x8*)(dst + 8) = o1;
}

// ---------------- MFMA GEMM: out[m][n] = A[m][:]·Bt[n][:] + bias (+resid) --
template<int OUTMODE>   // 0: bf16 out, no resid; 1: f32 out + f32 resid
__global__ __launch_bounds__(256)
void gemm_mfma(const ushort* __restrict__ A, const ushort* __restrict__ Bt,
               const float* __restrict__ bias, const float* __restrict__ resid,
               void* __restrict__ outp, int M, int N, int K,
               int nscale, float sfac)
{
    __shared__ ushort As[128 * 32];
    __shared__ ushort Bs[128 * 32];
    const int bn = blockIdx.x * 128;
    const int bm = blockIdx.y * 128;
    const int t  = threadIdx.x;
    const int w  = t >> 6, l = t & 63;
    const int lg = l >> 4, lr = l & 15;
    const int wr = w >> 1, wc = w & 1;

    f32x4 acc[4][4];
    #pragma unroll
    for (int i = 0; i < 4; ++i)
        #pragma unroll
        for (int j = 0; j < 4; ++j) acc[i][j] = (f32x4){0.f, 0.f, 0.f, 0.f};

    for (int k0 = 0; k0 < K; k0 += 32) {
        #pragma unroll
        for (int it = 0; it < 2; ++it) {
            const int g = it * 256 + t;
            const int r = g >> 2, cb = (g & 3) * 8;
            GLDS16(A  + (size_t)(bm + r) * K + k0 + cb, (char*)As + g * 16);
            GLDS16(Bt + (size_t)(bn + r) * K + k0 + cb, (char*)Bs + g * 16);
        }
        __syncthreads();
        bf16x8 af[4], bfr[4];
        #pragma unroll
        for (int m16 = 0; m16 < 4; ++m16)
            af[m16] = *(const bf16x8*)&As[(wr * 64 + m16 * 16 + lr) * 32 + lg * 8];
        #pragma unroll
        for (int n16 = 0; n16 < 4; ++n16)
            bfr[n16] = *(const bf16x8*)&Bs[(wc * 64 + n16 * 16 + lr) * 32 + lg * 8];
        #pragma unroll
        for (int m16 = 0; m16 < 4; ++m16)
            #pragma unroll
            for (int n16 = 0; n16 < 4; ++n16)
                acc[m16][n16] = __builtin_amdgcn_mfma_f32_16x16x32_bf16(
                    af[m16], bfr[n16], acc[m16][n16], 0, 0, 0);
        __syncthreads();
    }

    #pragma unroll
    for (int m16 = 0; m16 < 4; ++m16) {
        #pragma unroll
        for (int n16 = 0; n16 < 4; ++n16) {
            const int col = bn + wc * 64 + n16 * 16 + lr;
            const float bcol = bias[col];
            #pragma unroll
            for (int r = 0; r < 4; ++r) {
                const int row = bm + wr * 64 + m16 * 16 + lg * 4 + r;
                float v = acc[m16][n16][r] + bcol;
                if (OUTMODE == 1) {
                    v += resid[(size_t)row * N + col];
                    ((float*)outp)[(size_t)row * N + col] = v;
                } else {
                    if (col < nscale) v *= sfac;
                    ((ushort*)outp)[(size_t)row * N + col] = f2bf(v);
                }
            }
        }
    }
}

// ---------------- V transpose: bf16 [b*S+s][2304] col h*64+d -> [b][h][d][s]
__global__ __launch_bounds__(256)
void transpose_v(const ushort* __restrict__ Vsrc, ushort* __restrict__ Vt)
{
    const int s0 = blockIdx.x * 64;
    const int bh = blockIdx.y;
    const int b  = bh / NHEAD, h = bh % NHEAD;
    const int t  = threadIdx.x;
    __shared__ ushort T[64][65];

    const int r  = t >> 2;
    const int c0 = (t & 3) * 16;
    const ushort* src = Vsrc + (size_t)(b * S_LEN + s0 + r) * NQKV + h * HDIM + c0;
    bf16x8 a0 = *(const bf16x8*)src;
    bf16x8 a1 = *(const bf16x8*)(src + 8);
    #pragma unroll
    for (int j = 0; j < 8; ++j) { T[r][c0 + j] = a0[j]; T[r][c0 + 8 + j] = a1[j]; }
    __syncthreads();

    const int d = t >> 2, sc0 = (t & 3) * 16;
    bf16x8 o0, o1;
    #pragma unroll
    for (int j = 0; j < 8; ++j) {
        o0[j] = (short)T[sc0 + j][d];
        o1[j] = (short)T[sc0 + 8 + j][d];
    }
    ushort* dst = Vt + ((size_t)(b * NHEAD + h) * HDIM + d) * S_LEN + s0 + sc0;
    *(bf16x8*)dst       = o0;
    *(bf16x8*)(dst + 8) = o1;
}

// ---------------- MFMA flash attention, split-KV, direct-global K/V --------
// No K/V LDS staging: B-fragments for QK^T (contiguous d in K) and PV
// (contiguous s in Vt) are loaded straight from global (L2-resident).
// No barriers in the K-loop; only per-wave Ps LDS round-trip (lgkmcnt).
#define KT     64
#define ATT_QT 128
#define KVHALF (S_LEN / 2)

__global__ __launch_bounds__(256, 3)
void attn_mfma(const ushort* __restrict__ Qbf, const ushort* __restrict__ Kbf,
               const ushort* __restrict__ Vt, const float* __restrict__ mask,
               ushort* __restrict__ Pp, float* __restrict__ lp)
{
    const int qt = blockIdx.x, h = blockIdx.y;
    const int b  = blockIdx.z >> 1, half = blockIdx.z & 1;
    const int t  = threadIdx.x;
    const int w  = t >> 6, l = t & 63;
    const int lg = l >> 4, lr = l & 15;
    const int q0 = qt * ATT_QT;
    const int kb0 = half * KVHALF;

    __shared__ ushort Ps[4][32][64];     // per-wave P [q][kv], swizzled, 16 KB
    __shared__ float  kmarg[KVHALF];     // 4 KB: 0 valid / -1e30 masked

    // stage kv-mask args once (coalesced f32x4)
    {
        const int i = t * 4;
        f32x4 v = *(const f32x4*)(mask + b * S_LEN + kb0 + i);
        #pragma unroll
        for (int j = 0; j < 4; ++j)
            kmarg[i + j] = (v[j] >= 0.f) ? 0.f : -1e30f;
    }

    // q-row validity, 2 groups x 4 rows
    bool qn[2][4];
    #pragma unroll
    for (int qg = 0; qg < 2; ++qg)
        #pragma unroll
        for (int r = 0; r < 4; ++r)
            qn[qg][r] = (mask[b * S_LEN + q0 + w * 32 + qg * 16 + lg * 4 + r] < 0.f);

    // Q A-fragments (pre-scaled by SM_C in QKV GEMM epilogue)
    bf16x8 qa[2][2];
    #pragma unroll
    for (int qg = 0; qg < 2; ++qg) {
        const ushort* qsrc = Qbf
            + (size_t)(b * S_LEN + q0 + w * 32 + qg * 16 + lr) * NQKV
            + h * HDIM + lg * 8;
        qa[qg][0] = *(const bf16x8*)qsrc;
        qa[qg][1] = *(const bf16x8*)(qsrc + 32);
    }

    // per-lane base pointers for direct B-fragment loads
    // K frag (ct,kb): kLane + (k0 + 16ct)*NQKV + kb*32
    const ushort* kLane = Kbf + ((size_t)(b * S_LEN + kb0) + lr) * NQKV
                        + h * HDIM + lg * 8;
    // V frag (ct,kvb): vLane + (16ct)*S_LEN + (k0-kb0) + kvb*32
    const ushort* vLane = Vt + (((size_t)(b * NHEAD + h) * HDIM) + lr) * S_LEN
                        + kb0 + lg * 8;

    __syncthreads();   // kmarg visible; the only barrier in this kernel

    float l_r[2][4] = {{0.f,0.f,0.f,0.f},{0.f,0.f,0.f,0.f}};
    f32x4 accO[2][4];
    #pragma unroll
    for (int qg = 0; qg < 2; ++qg)
        #pragma unroll
        for (int ct = 0; ct < 4; ++ct) accO[qg][ct] = (f32x4){0.f,0.f,0.f,0.f};

    const int  swz = (lr & 7) << 4;
    char* PsW = (char*)Ps + w * 4096;

    for (int kk = 0; kk < KVHALF; kk += KT) {
        // kv-mask additive args from LDS (broadcast)
        float karr[4];
        #pragma unroll
        for (int ct = 0; ct < 4; ++ct)
            karr[ct] = kmarg[kk + 16 * ct + lr];

        // ---- K B-frags direct from global (contiguous 16B per lane) ----
        const ushort* kp = kLane + (size_t)kk * NQKV;
        bf16x8 bk[4][2];
        #pragma unroll
        for (int ct = 0; ct < 4; ++ct) {
            bk[ct][0] = *(const bf16x8*)(kp + (size_t)(16 * ct) * NQKV);
            bk[ct][1] = *(const bf16x8*)(kp + (size_t)(16 * ct) * NQKV + 32);
        }

        // ---- S = Q·K^T (scale folded into Q) ----
        f32x4 sc[2][4];
        __builtin_amdgcn_s_setprio(1);
        #pragma unroll
        for (int ct = 0; ct < 4; ++ct) {
            #pragma unroll
            for (int qg = 0; qg < 2; ++qg) {
                f32x4 a = __builtin_amdgcn_mfma_f32_16x16x32_bf16(
                    qa[qg][0], bk[ct][0], (f32x4){0.f,0.f,0.f,0.f}, 0, 0, 0);
                sc[qg][ct] = __builtin_amdgcn_mfma_f32_16x16x32_bf16(
                    qa[qg][1], bk[ct][1], a, 0, 0, 0);
            }
        }
        __builtin_amdgcn_s_setprio(0);

        // ---- V B-frags direct from global (issue early, used after softmax)
        const ushort* vp = vLane + kk;
        bf16x8 bv[4][2];
        #pragma unroll
        for (int ct = 0; ct < 4; ++ct) {
            bv[ct][0] = *(const bf16x8*)(vp + (size_t)(16 * ct) * S_LEN);
            bv[ct][1] = *(const bf16x8*)(vp + (size_t)(16 * ct) * S_LEN + 32);
        }

        // ---- p = exp2(arg); per-lane denominator accumulate ----
        #pragma unroll
        for (int qg = 0; qg < 2; ++qg) {
            #pragma unroll
            for (int r = 0; r < 4; ++r) {
                const int qrow = qg * 16 + lg * 4 + r;
                const int qsw  = (qrow & 7) << 4;
                #pragma unroll
                for (int ct = 0; ct < 4; ++ct) {
                    float arg = sc[qg][ct][r] + karr[ct];
                    arg = qn[qg][r] ? 0.f : arg;
                    const float p = exp2f(arg);
                    l_r[qg][r] += p;
                    *(ushort*)(PsW + qrow * 128 + ((32 * ct + 2 * lr) ^ qsw)) = f2bf(p);
                }
            }
        }

        // ---- O += P·V ----
        __builtin_amdgcn_s_setprio(1);
        #pragma unroll
        for (int kvb = 0; kvb < 2; ++kvb) {
            bf16x8 pa0 = *(const bf16x8*)(PsW + lr * 128
                                          + ((lg * 16 + kvb * 64) ^ swz));
            bf16x8 pa1 = *(const bf16x8*)(PsW + (16 + lr) * 128
                                          + ((lg * 16 + kvb * 64) ^ swz));
            #pragma unroll
            for (int ct = 0; ct < 4; ++ct) {
                accO[0][ct] = __builtin_amdgcn_mfma_f32_16x16x32_bf16(pa0, bv[ct][kvb], accO[0][ct], 0, 0, 0);
                accO[1][ct] = __builtin_amdgcn_mfma_f32_16x16x32_bf16(pa1, bv[ct][kvb], accO[1][ct], 0, 0, 0);
            }
        }
        __builtin_amdgcn_s_setprio(0);
    }

    // denominator reduce across the 16 lanes of each row group
    #pragma unroll
    for (int qg = 0; qg < 2; ++qg)
        #pragma unroll
        for (int r = 0; r < 4; ++r) {
            float s = l_r[qg][r];
            #pragma unroll
            for (int off = 1; off < 16; off <<= 1)
                s += __shfl_xor(s, off, 64);
            l_r[qg][r] = s;
        }

    // write unnormalized partial O (bf16) + l (f32)
    const size_t MN = (size_t)M_TOT * H_DIM;
    #pragma unroll
    for (int qg = 0; qg < 2; ++qg) {
        #pragma unroll
        for (int r = 0; r < 4; ++r) {
            const int m = b * S_LEN + q0 + w * 32 + qg * 16 + lg * 4 + r;
            const size_t base = (size_t)half * MN + (size_t)m * H_DIM + h * HDIM;
            #pragma unroll
            for (int ct = 0; ct < 4; ++ct)
                Pp[base + 16 * ct + lr] = f2bf(accO[qg][ct][r]);
            if (lr == 0)
                lp[half * (M_TOT * NHEAD) + m * NHEAD + h] = l_r[qg][r];
        }
    }
}

// ---------------- combine: ctx = (P0+P1)/(l0+l1) ---------------------------
__global__ __launch_bounds__(256)
void combine_kernel(const ushort* __restrict__ Pp, const float* __restrict__ lp,
                    ushort* __restrict__ ctx)
{
    const int idx = blockIdx.x * 256 + threadIdx.x;   // over M_TOT*96
    const int m  = idx / 96;
    const int c8 = idx % 96;
    const int c  = c8 * 8;
    const int h  = c8 >> 3;
    const size_t MN = (size_t)M_TOT * H_DIM;

    const float lsum = lp[m * NHEAD + h] + lp[M_TOT * NHEAD + m * NHEAD + h];
    const float inv  = 1.0f / lsum;

    bf16x8 a = *(const bf16x8*)(Pp + (size_t)m * H_DIM + c);
    bf16x8 b = *(const bf16x8*)(Pp + MN + (size_t)m * H_DIM + c);
    bf16x8 o;
    #pragma unroll
    for (int j = 0; j < 8; ++j)
        o[j] = (short)f2bf((bf2f((ushort)a[j]) + bf2f((ushort)b[j])) * inv);
    *(bf16x8*)(ctx + (size_t)m * H_DIM + c) = o;
}

// ---------------- LayerNorm ------------------------------------------------
__global__ __launch_bounds__(256)
void ln_kernel(const float* __restrict__ Hbuf, const float* __restrict__ gamma,
               const float* __restrict__ beta, float* __restrict__ out)
{
    const int m = blockIdx.x;
    const int t = threadIdx.x;
    const float* row = Hbuf + (size_t)m * H_DIM;
    __shared__ float red[256];
    float x[3];
    #pragma unroll
    for (int i = 0; i < 3; ++i) x[i] = row[t + i * 256];

    red[t] = x[0] + x[1] + x[2];
    __syncthreads();
    for (int off = 128; off > 0; off >>= 1) {
        if (t < off) red[t] += red[t + off];
        __syncthreads();
    }
    const float mu = red[0] * (1.0f / H_DIM);
    __syncthreads();

    float d0 = x[0] - mu, d1 = x[1] - mu, d2 = x[2] - mu;
    red[t] = d0 * d0 + d1 * d1 + d2 * d2;
    __syncthreads();
    for (int off = 128; off > 0; off >>= 1) {
        if (t < off) red[t] += red[t + off];
        __syncthreads();
    }
    const float var  = red[0] * (1.0f / H_DIM);
    const float rstd = rsqrtf(var + LN_EPS);
    #pragma unroll
    for (int i = 0; i < 3; ++i) {
        int c = t + i * 256;
        out[(size_t)m * H_DIM + c] = (x[i] - mu) * rstd * gamma[c] + beta[c];
    }
}

// ---------------------------------------------------------------------------
extern "C" void kernel_launch(void* const* d_in, const int* in_sizes, int n_in,
                              void* d_out, int out_size, void* d_ws, size_t ws_size,
                              hipStream_t stream)
{
    const float* hs   = (const float*)d_in[0];
    const float* mask = (const float*)d_in[1];
    const float* Wq   = (const float*)d_in[2];
    const float* bq   = (const float*)d_in[3];
    const float* Wk   = (const float*)d_in[4];
    const float* bk   = (const float*)d_in[5];
    const float* Wv   = (const float*)d_in[6];
    const float* bv   = (const float*)d_in[7];
    const float* Wo   = (const float*)d_in[8];
    const float* bo   = (const float*)d_in[9];
    const float* g    = (const float*)d_in[10];
    const float* be   = (const float*)d_in[11];
    float* out = (float*)d_out;

    char* base = (char*)d_ws;
    ushort* Xbf    = (ushort*)(base);                    //  6,291,456 B
    ushort* QKVbf  = (ushort*)(base + 6291456);          // 18,874,368 B
    ushort* Wcat   = (ushort*)(base + 25165824);         //  3,538,944 B (lp after QKV gemm)
    ushort* Wot    = (ushort*)(base + 28704768);         //  1,179,648 B
    float*  bcat   = (float*) (base + 29884416);         //      9,216 B
    ushort* Vt     = (ushort*)(base + 29893632);         //  6,291,456 B
    ushort* Cbf    = (ushort*)(base + 36185088);         //  6,291,456 B
    float*  Hb     = (float*) (base + 42476544);         // 12,582,912 B (Pp before out-GEMM)
    float*  lp     = (float*) (base + 25165824);         // reuse Wcat region (393,216 B)
    ushort* Pp     = (ushort*)(base + 42476544);         // reuse Hb region (12,582,912 B)

    convert_x<<<M_TOT * H_DIM / 1024, 256, 0, stream>>>(hs, Xbf);
    concat_bias<<<9, 256, 0, stream>>>(bq, bk, bv, bcat);
    convert_w<<<dim3(12, 12, 4), 256, 0, stream>>>(Wq, Wk, Wv, Wo, Wcat, Wot);

    // Q columns (< 768) pre-scaled by 0.125*log2(e) so attention can exp2 directly
    gemm_mfma<0><<<dim3(NQKV / 128, M_TOT / 128), 256, 0, stream>>>(
        Xbf, Wcat, bcat, nullptr, QKVbf, M_TOT, NQKV, H_DIM, 768, SM_C);

    transpose_v<<<dim3(S_LEN / 64, B_SZ * NHEAD), 256, 0, stream>>>(QKVbf + 1536, Vt);

    attn_mfma<<<dim3(S_LEN / ATT_QT, NHEAD, B_SZ * 2), 256, 0, stream>>>(
        QKVbf, QKVbf + 768, Vt, mask, Pp, lp);

    combine_kernel<<<M_TOT * 96 / 256, 256, 0, stream>>>(Pp, lp, Cbf);

    gemm_mfma<1><<<dim3(H_DIM / 128, M_TOT / 128), 256, 0, stream>>>(
        Cbf, Wot, bo, hs, Hb, M_TOT, H_DIM, H_DIM, 0, 1.0f);

    ln_kernel<<<M_TOT, 256, 0, stream>>>(Hb, g, be, out);
}

// Round 9
// 128.678 us; speedup vs baseline: 1.4457x; 1.4457x over previous
//
#include <hip/hip_runtime.h>
#include <hip/hip_bf16.h>

#define H_DIM 768
#define NHEAD 12
#define HDIM  64
#define S_LEN 2048
#define B_SZ  2
#define M_TOT (B_SZ * S_LEN)   // 4096
#define NQKV  (3 * H_DIM)      // 2304
#define LN_EPS 1e-5f
#define SM_C   0.1803368801f   // 0.125 * log2(e)

typedef __attribute__((ext_vector_type(8))) short bf16x8;
typedef __attribute__((ext_vector_type(4))) float f32x4;

static __device__ inline ushort f2bf(float x) {
    __hip_bfloat16 h = __float2bfloat16(x);
    ushort u;
    __builtin_memcpy(&u, &h, 2);
    return u;
}
static __device__ inline float bf2f(ushort u) {
    unsigned int v = ((unsigned int)u) << 16;
    float f;
    __builtin_memcpy(&f, &v, 4);
    return f;
}

#define GLDS16(g, l) __builtin_amdgcn_global_load_lds( \
    (const __attribute__((address_space(1))) void*)(g), \
    (__attribute__((address_space(3))) void*)(l), 16, 0, 0)

// ---------------- prep: convert_x + convert_w + concat_bias (fused) --------
__global__ __launch_bounds__(256)
void prep(const float* __restrict__ hs,
          const float* __restrict__ Wq, const float* __restrict__ Wk,
          const float* __restrict__ Wv, const float* __restrict__ Wo,
          const float* __restrict__ bq, const float* __restrict__ bk,
          const float* __restrict__ bv,
          ushort* __restrict__ Xbf, ushort* __restrict__ Wcat,
          ushort* __restrict__ Wot, float* __restrict__ bcat)
{
    __shared__ ushort T[64][65];
    const int bid = blockIdx.x;
    const int t   = threadIdx.x;

    if (bid < 3072) {                       // convert_x
        const int i = (bid * 256 + t) * 4;
        f32x4 v = *(const f32x4*)(hs + i);
        ushort4 o;
        o.x = f2bf(v[0]); o.y = f2bf(v[1]); o.z = f2bf(v[2]); o.w = f2bf(v[3]);
        *(ushort4*)(Xbf + i) = o;
    } else if (bid < 3072 + 576) {          // convert_w (transpose to [n][k])
        const int bid2 = bid - 3072;
        const int z = bid2 / 144;
        const int rem = bid2 % 144;
        const int n0 = (rem / 12) * 64;
        const int k0 = (rem % 12) * 64;
        const float* W = (z == 0) ? Wq : (z == 1) ? Wk : (z == 2) ? Wv : Wo;
        const int r = t >> 2, c0 = (t & 3) * 16;
        const float* src = W + (size_t)(k0 + r) * H_DIM + n0 + c0;
        #pragma unroll
        for (int j = 0; j < 16; j += 4) {
            f32x4 v = *(const f32x4*)(src + j);
            #pragma unroll
            for (int jj = 0; jj < 4; ++jj) T[r][c0 + j + jj] = f2bf(v[jj]);
        }
        __syncthreads();
        bf16x8 o0, o1;
        #pragma unroll
        for (int j = 0; j < 8; ++j) {
            o0[j] = (short)T[c0 + j][r];
            o1[j] = (short)T[c0 + 8 + j][r];
        }
        ushort* dst = (z < 3)
            ? Wcat + (size_t)(z * 768 + n0 + r) * H_DIM + k0 + c0
            : Wot  + (size_t)(n0 + r) * H_DIM + k0 + c0;
        *(bf16x8*)dst       = o0;
        *(bf16x8*)(dst + 8) = o1;
    } else {                                // concat_bias
        const int i = (bid - 3648) * 256 + t;
        if (i < NQKV) {
            float v = (i < 768) ? bq[i] : (i < 1536) ? bk[i - 768] : bv[i - 1536];
            bcat[i] = v;
        }
    }
}

// ---------------- MFMA GEMM: out[m][n] = A[m][:]·Bt[n][:] + bias (+resid) --
// OUTMODE 0: bf16 out; cols<nscale scaled by sfac; cols>=1536 go TRANSPOSED
//            into vtp as [b][h][d][s] (V fused transpose), not into outp.
// OUTMODE 1: f32 out + f32 resid.
template<int OUTMODE>
__global__ __launch_bounds__(256)
void gemm_mfma(const ushort* __restrict__ A, const ushort* __restrict__ Bt,
               const float* __restrict__ bias, const float* __restrict__ resid,
               void* __restrict__ outp, ushort* __restrict__ vtp,
               int M, int N, int K, int nscale, float sfac)
{
    __shared__ ushort As[128 * 32];
    __shared__ ushort Bs[128 * 32];
    const int bn = blockIdx.x * 128;
    const int bm = blockIdx.y * 128;
    const int t  = threadIdx.x;
    const int w  = t >> 6, l = t & 63;
    const int lg = l >> 4, lr = l & 15;
    const int wr = w >> 1, wc = w & 1;

    f32x4 acc[4][4];
    #pragma unroll
    for (int i = 0; i < 4; ++i)
        #pragma unroll
        for (int j = 0; j < 4; ++j) acc[i][j] = (f32x4){0.f, 0.f, 0.f, 0.f};

    for (int k0 = 0; k0 < K; k0 += 32) {
        #pragma unroll
        for (int it = 0; it < 2; ++it) {
            const int g = it * 256 + t;
            const int r = g >> 2, cb = (g & 3) * 8;
            GLDS16(A  + (size_t)(bm + r) * K + k0 + cb, (char*)As + g * 16);
            GLDS16(Bt + (size_t)(bn + r) * K + k0 + cb, (char*)Bs + g * 16);
        }
        __syncthreads();
        bf16x8 af[4], bfr[4];
        #pragma unroll
        for (int m16 = 0; m16 < 4; ++m16)
            af[m16] = *(const bf16x8*)&As[(wr * 64 + m16 * 16 + lr) * 32 + lg * 8];
        #pragma unroll
        for (int n16 = 0; n16 < 4; ++n16)
            bfr[n16] = *(const bf16x8*)&Bs[(wc * 64 + n16 * 16 + lr) * 32 + lg * 8];
        #pragma unroll
        for (int m16 = 0; m16 < 4; ++m16)
            #pragma unroll
            for (int n16 = 0; n16 < 4; ++n16)
                acc[m16][n16] = __builtin_amdgcn_mfma_f32_16x16x32_bf16(
                    af[m16], bfr[n16], acc[m16][n16], 0, 0, 0);
        __syncthreads();
    }

    #pragma unroll
    for (int m16 = 0; m16 < 4; ++m16) {
        #pragma unroll
        for (int n16 = 0; n16 < 4; ++n16) {
            const int col = bn + wc * 64 + n16 * 16 + lr;
            const float bcol = bias[col];
            const int row0 = bm + wr * 64 + m16 * 16 + lg * 4;
            float vv[4];
            #pragma unroll
            for (int r = 0; r < 4; ++r) {
                float v = acc[m16][n16][r] + bcol;
                if (OUTMODE == 1) v += resid[(size_t)(row0 + r) * N + col];
                else if (col < nscale) v *= sfac;
                vv[r] = v;
            }
            if (OUTMODE == 1) {
                #pragma unroll
                for (int r = 0; r < 4; ++r)
                    ((float*)outp)[(size_t)(row0 + r) * N + col] = vv[r];
            } else if (col >= 1536) {
                // V: fused transpose store, 4 consecutive s -> one 8B store
                const int dfull = col - 1536;
                const int hh = dfull >> 6, dd = dfull & 63;
                const int bb = row0 >> 11, ss = row0 & 2047;
                ushort4 pk;
                pk.x = f2bf(vv[0]); pk.y = f2bf(vv[1]);
                pk.z = f2bf(vv[2]); pk.w = f2bf(vv[3]);
                *(ushort4*)(vtp + ((size_t)(bb * NHEAD + hh) * HDIM + dd) * S_LEN + ss) = pk;
            } else {
                #pragma unroll
                for (int r = 0; r < 4; ++r)
                    ((ushort*)outp)[(size_t)(row0 + r) * N + col] = f2bf(vv[r]);
            }
        }
    }
}

// ---------------- MFMA flash attention, split-KV, counted-vmcnt pipeline ---
// K: 3-buffer depth-2 prefetch; V: 2-buffer depth-1. Raw s_barrier + counted
// asm vmcnt(2) keeps prefetches in flight across the barrier (T4). Issue
// order per tile: [wait vmcnt(2); barrier; issue V(t+1),K(t+2); compute t].
// Only VMEM in the loop = our 4 global_load_lds, so vmcnt counts are exact.
#define KT     64
#define ATT_QT 128
#define KVHALF (S_LEN / 2)
#define NTILES (KVHALF / KT)   // 16

__global__ __launch_bounds__(256, 3)
void attn_mfma(const ushort* __restrict__ Qbf, const ushort* __restrict__ Kbf,
               const ushort* __restrict__ Vt, const float* __restrict__ mask,
               ushort* __restrict__ Pp, float* __restrict__ lp)
{
    const int qt = blockIdx.x, h = blockIdx.y;
    const int b  = blockIdx.z >> 1, half = blockIdx.z & 1;
    const int t  = threadIdx.x;
    const int w  = t >> 6, l = t & 63;
    const int lg = l >> 4, lr = l & 15;
    const int q0 = qt * ATT_QT;
    const int kb0 = half * KVHALF;

    __shared__ ushort Ks[3][KT][64];     // 24 KB, swizzled
    __shared__ ushort Vs[2][HDIM][64];   // 16 KB, swizzled
    __shared__ ushort Ps[4][16][64];     //  8 KB (2 KB/wave, qg-sequential)
    __shared__ float  kmarg[KVHALF];     //  4 KB: 0 valid / -1e30 masked

    {   // stage kv-mask args once (coalesced f32x4)
        const int i = t * 4;
        f32x4 v = *(const f32x4*)(mask + b * S_LEN + kb0 + i);
        #pragma unroll
        for (int j = 0; j < 4; ++j)
            kmarg[i + j] = (v[j] >= 0.f) ? 0.f : -1e30f;
    }

    bool qn[2][4];
    #pragma unroll
    for (int qg = 0; qg < 2; ++qg)
        #pragma unroll
        for (int r = 0; r < 4; ++r)
            qn[qg][r] = (mask[b * S_LEN + q0 + w * 32 + qg * 16 + lg * 4 + r] < 0.f);

    // Q A-fragments (pre-scaled by SM_C in QKV GEMM epilogue)
    bf16x8 qa[2][2];
    #pragma unroll
    for (int qg = 0; qg < 2; ++qg) {
        const ushort* qsrc = Qbf
            + (size_t)(b * S_LEN + q0 + w * 32 + qg * 16 + lr) * NQKV
            + h * HDIM + lg * 8;
        qa[qg][0] = *(const bf16x8*)qsrc;
        qa[qg][1] = *(const bf16x8*)(qsrc + 32);
    }

    // staging geometry (T2 swizzle: source column pre-swizzled, LDS linear)
    const int srow = w * 16 + (l >> 3);
    const int scol = ((l & 7) ^ (l >> 3)) * 8;
    const ushort* kLane = Kbf + (size_t)(b * S_LEN + kb0 + srow) * NQKV
                        + h * HDIM + scol;
    const ushort* vLane = Vt + ((size_t)(b * NHEAD + h) * HDIM + srow) * S_LEN
                        + kb0 + scol;
    char* ldsK = (char*)Ks + w * 2048 + l * 16;   // + buf*8192, +1024 inst 1
    char* ldsV = (char*)Vs + w * 2048 + l * 16;

    __syncthreads();   // kmarg visible; drains ALL outstanding vmem to 0

    // prologue: K(0), V(0), K(1)  -> queue order matters for vmcnt counts
    GLDS16(kLane, ldsK);
    GLDS16(kLane + (size_t)8 * NQKV, ldsK + 1024);
    GLDS16(vLane, ldsV);
    GLDS16(vLane + (size_t)8 * S_LEN, ldsV + 1024);
    GLDS16(kLane + (size_t)KT * NQKV, ldsK + 8192);
    GLDS16(kLane + (size_t)(KT + 8) * NQKV, ldsK + 8192 + 1024);

    float l_r[2][4] = {{0.f,0.f,0.f,0.f},{0.f,0.f,0.f,0.f}};
    f32x4 accO[2][4];
    #pragma unroll
    for (int qg = 0; qg < 2; ++qg)
        #pragma unroll
        for (int ct = 0; ct < 4; ++ct) accO[qg][ct] = (f32x4){0.f,0.f,0.f,0.f};

    const int  swz = (lr & 7) << 4;
    char* PsW = (char*)Ps + w * 2048;

    for (int tt = 0; tt < NTILES; ++tt) {
        // ---- counted wait: tile tt's K+V done, K(tt+1) may stay in flight --
        if (tt < NTILES - 1) {
            asm volatile("s_waitcnt vmcnt(2)" ::: "memory");
        } else {
            asm volatile("s_waitcnt vmcnt(0)" ::: "memory");
        }
        __builtin_amdgcn_s_barrier();

        // ---- issue prefetch: V(tt+1) depth-1, K(tt+2) depth-2 ----
        if (tt + 1 < NTILES) {
            const ushort* vsrc = vLane + (size_t)(tt + 1) * KT;
            char* lv = ldsV + ((tt + 1) & 1) * 8192;
            GLDS16(vsrc, lv);
            GLDS16(vsrc + (size_t)8 * S_LEN, lv + 1024);
            if (tt + 2 < NTILES) {
                const ushort* ksrc = kLane + (size_t)(tt + 2) * KT * NQKV;
                char* lk = ldsK + ((tt + 2) % 3) * 8192;
                GLDS16(ksrc, lk);
                GLDS16(ksrc + (size_t)8 * NQKV, lk + 1024);
            }
        }

        const char* Kc = (const char*)Ks + (tt % 3) * 8192;
        const char* Vc = (const char*)Vs + (tt & 1) * 8192;

        float karr[4];
        #pragma unroll
        for (int ct = 0; ct < 4; ++ct)
            karr[ct] = kmarg[tt * KT + 16 * ct + lr];

        // ---- S = Q·K^T (scale folded into Q), both q-groups ----
        f32x4 sc[2][4];
        __builtin_amdgcn_s_setprio(1);
        #pragma unroll
        for (int ct = 0; ct < 4; ++ct) {
            bf16x8 bk0 = *(const bf16x8*)(Kc + (16 * ct + lr) * 128 + ((lg * 16) ^ swz));
            bf16x8 bk1 = *(const bf16x8*)(Kc + (16 * ct + lr) * 128 + ((lg * 16 + 64) ^ swz));
            #pragma unroll
            for (int qg = 0; qg < 2; ++qg) {
                f32x4 a = __builtin_amdgcn_mfma_f32_16x16x32_bf16(
                    qa[qg][0], bk0, (f32x4){0.f,0.f,0.f,0.f}, 0, 0, 0);
                sc[qg][ct] = __builtin_amdgcn_mfma_f32_16x16x32_bf16(
                    qa[qg][1], bk1, a, 0, 0, 0);
            }
        }
        __builtin_amdgcn_s_setprio(0);

        // ---- V B-frags into regs once, shared across both q-groups ----
        bf16x8 bv[4][2];
        #pragma unroll
        for (int ct = 0; ct < 4; ++ct) {
            bv[ct][0] = *(const bf16x8*)(Vc + (16 * ct + lr) * 128 + ((lg * 16) ^ swz));
            bv[ct][1] = *(const bf16x8*)(Vc + (16 * ct + lr) * 128 + ((lg * 16 + 64) ^ swz));
        }

        // ---- per q-group: softmax -> Ps (2KB/wave) -> PV ----
        #pragma unroll
        for (int qg = 0; qg < 2; ++qg) {
            #pragma unroll
            for (int r = 0; r < 4; ++r) {
                const int qrow = lg * 4 + r;
                const int qsw  = (qrow & 7) << 4;
                #pragma unroll
                for (int ct = 0; ct < 4; ++ct) {
                    float arg = sc[qg][ct][r] + karr[ct];
                    arg = qn[qg][r] ? 0.f : arg;
                    const float p = exp2f(arg);
                    l_r[qg][r] += p;
                    *(ushort*)(PsW + qrow * 128 + ((32 * ct + 2 * lr) ^ qsw)) = f2bf(p);
                }
            }
            __builtin_amdgcn_s_setprio(1);
            #pragma unroll
            for (int kvb = 0; kvb < 2; ++kvb) {
                bf16x8 pa = *(const bf16x8*)(PsW + lr * 128
                                             + ((lg * 16 + kvb * 64) ^ swz));
                #pragma unroll
                for (int ct = 0; ct < 4; ++ct)
                    accO[qg][ct] = __builtin_amdgcn_mfma_f32_16x16x32_bf16(
                        pa, bv[ct][kvb], accO[qg][ct], 0, 0, 0);
            }
            __builtin_amdgcn_s_setprio(0);
        }
    }

    // denominator reduce across the 16 lanes of each row group
    #pragma unroll
    for (int qg = 0; qg < 2; ++qg)
        #pragma unroll
        for (int r = 0; r < 4; ++r) {
            float s = l_r[qg][r];
            #pragma unroll
            for (int off = 1; off < 16; off <<= 1)
                s += __shfl_xor(s, off, 64);
            l_r[qg][r] = s;
        }

    // write unnormalized partial O (bf16) + l (f32)
    const size_t MN = (size_t)M_TOT * H_DIM;
    #pragma unroll
    for (int qg = 0; qg < 2; ++qg) {
        #pragma unroll
        for (int r = 0; r < 4; ++r) {
            const int m = b * S_LEN + q0 + w * 32 + qg * 16 + lg * 4 + r;
            const size_t base = (size_t)half * MN + (size_t)m * H_DIM + h * HDIM;
            #pragma unroll
            for (int ct = 0; ct < 4; ++ct)
                Pp[base + 16 * ct + lr] = f2bf(accO[qg][ct][r]);
            if (lr == 0)
                lp[half * (M_TOT * NHEAD) + m * NHEAD + h] = l_r[qg][r];
        }
    }
}

// ---------------- combine: ctx = (P0+P1)/(l0+l1) ---------------------------
__global__ __launch_bounds__(256)
void combine_kernel(const ushort* __restrict__ Pp, const float* __restrict__ lp,
                    ushort* __restrict__ ctx)
{
    const int idx = blockIdx.x * 256 + threadIdx.x;   // over M_TOT*96
    const int m  = idx / 96;
    const int c8 = idx % 96;
    const int c  = c8 * 8;
    const int h  = c8 >> 3;
    const size_t MN = (size_t)M_TOT * H_DIM;

    const float lsum = lp[m * NHEAD + h] + lp[M_TOT * NHEAD + m * NHEAD + h];
    const float inv  = 1.0f / lsum;

    bf16x8 a = *(const bf16x8*)(Pp + (size_t)m * H_DIM + c);
    bf16x8 b = *(const bf16x8*)(Pp + MN + (size_t)m * H_DIM + c);
    bf16x8 o;
    #pragma unroll
    for (int j = 0; j < 8; ++j)
        o[j] = (short)f2bf((bf2f((ushort)a[j]) + bf2f((ushort)b[j])) * inv);
    *(bf16x8*)(ctx + (size_t)m * H_DIM + c) = o;
}

// ---------------- LayerNorm (wave-per-row, shuffle reduce, no LDS) ---------
__global__ __launch_bounds__(256)
void ln_kernel(const float* __restrict__ Hbuf, const float* __restrict__ gamma,
               const float* __restrict__ beta, float* __restrict__ out)
{
    const int m = blockIdx.x * 4 + (threadIdx.x >> 6);
    const int l = threadIdx.x & 63;
    const float* row = Hbuf + (size_t)m * H_DIM;

    f32x4 x[3];
    #pragma unroll
    for (int k = 0; k < 3; ++k) x[k] = *(const f32x4*)(row + l * 4 + k * 256);

    float s = 0.f;
    #pragma unroll
    for (int k = 0; k < 3; ++k)
        #pragma unroll
        for (int j = 0; j < 4; ++j) s += x[k][j];
    #pragma unroll
    for (int off = 1; off < 64; off <<= 1) s += __shfl_xor(s, off, 64);
    const float mu = s * (1.0f / H_DIM);

    float v = 0.f;
    #pragma unroll
    for (int k = 0; k < 3; ++k)
        #pragma unroll
        for (int j = 0; j < 4; ++j) {
            const float d = x[k][j] - mu;
            v += d * d;
        }
    #pragma unroll
    for (int off = 1; off < 64; off <<= 1) v += __shfl_xor(v, off, 64);
    const float rstd = rsqrtf(v * (1.0f / H_DIM) + LN_EPS);

    #pragma unroll
    for (int k = 0; k < 3; ++k) {
        const int c = l * 4 + k * 256;
        f32x4 gm = *(const f32x4*)(gamma + c);
        f32x4 bt = *(const f32x4*)(beta + c);
        f32x4 o;
        #pragma unroll
        for (int j = 0; j < 4; ++j)
            o[j] = (x[k][j] - mu) * rstd * gm[j] + bt[j];
        *(f32x4*)(out + (size_t)m * H_DIM + c) = o;
    }
}

// ---------------------------------------------------------------------------
extern "C" void kernel_launch(void* const* d_in, const int* in_sizes, int n_in,
                              void* d_out, int out_size, void* d_ws, size_t ws_size,
                              hipStream_t stream)
{
    const float* hs   = (const float*)d_in[0];
    const float* mask = (const float*)d_in[1];
    const float* Wq   = (const float*)d_in[2];
    const float* bq   = (const float*)d_in[3];
    const float* Wk   = (const float*)d_in[4];
    const float* bk   = (const float*)d_in[5];
    const float* Wv   = (const float*)d_in[6];
    const float* bv   = (const float*)d_in[7];
    const float* Wo   = (const float*)d_in[8];
    const float* bo   = (const float*)d_in[9];
    const float* g    = (const float*)d_in[10];
    const float* be   = (const float*)d_in[11];
    float* out = (float*)d_out;

    char* base = (char*)d_ws;
    ushort* Xbf    = (ushort*)(base);                    //  6,291,456 B
    ushort* QKVbf  = (ushort*)(base + 6291456);          // 18,874,368 B
    ushort* Wcat   = (ushort*)(base + 25165824);         //  3,538,944 B (lp after QKV gemm)
    ushort* Wot    = (ushort*)(base + 28704768);         //  1,179,648 B
    float*  bcat   = (float*) (base + 29884416);         //      9,216 B
    ushort* Vt     = (ushort*)(base + 29893632);         //  6,291,456 B
    ushort* Cbf    = (ushort*)(base + 36185088);         //  6,291,456 B
    float*  Hb     = (float*) (base + 42476544);         // 12,582,912 B (Pp before out-GEMM)
    float*  lp     = (float*) (base + 25165824);         // reuse Wcat region
    ushort* Pp     = (ushort*)(base + 42476544);         // reuse Hb region

    prep<<<3657, 256, 0, stream>>>(hs, Wq, Wk, Wv, Wo, bq, bk, bv,
                                   Xbf, Wcat, Wot, bcat);

    // Q cols (<768) pre-scaled by SM_C; V cols (>=1536) fused-transposed to Vt
    gemm_mfma<0><<<dim3(NQKV / 128, M_TOT / 128), 256, 0, stream>>>(
        Xbf, Wcat, bcat, nullptr, QKVbf, Vt, M_TOT, NQKV, H_DIM, 768, SM_C);

    attn_mfma<<<dim3(S_LEN / ATT_QT, NHEAD, B_SZ * 2), 256, 0, stream>>>(
        QKVbf, QKVbf + 768, Vt, mask, Pp, lp);

    combine_kernel<<<M_TOT * 96 / 256, 256, 0, stream>>>(Pp, lp, Cbf);

    gemm_mfma<1><<<dim3(H_DIM / 128, M_TOT / 128), 256, 0, stream>>>(
        Cbf, Wot, bo, hs, Hb, nullptr, M_TOT, H_DIM, H_DIM, 0, 1.0f);

    ln_kernel<<<M_TOT / 4, 256, 0, stream>>>(Hb, g, be, out);
}

// Round 10
// 125.608 us; speedup vs baseline: 1.4810x; 1.0244x over previous
//
#include <hip/hip_runtime.h>
#include <hip/hip_bf16.h>

#define H_DIM 768
#define NHEAD 12
#define HDIM  64
#define S_LEN 2048
#define B_SZ  2
#define M_TOT (B_SZ * S_LEN)   // 4096
#define NQKV  (3 * H_DIM)      // 2304
#define LN_EPS 1e-5f
#define SM_C   0.1803368801f   // 0.125 * log2(e)

typedef __attribute__((ext_vector_type(8)))  short bf16x8;
typedef __attribute__((ext_vector_type(4)))  float f32x4;
typedef __attribute__((ext_vector_type(16))) float f32x16;
typedef __attribute__((ext_vector_type(4)))  int   i32x4;
typedef __attribute__((ext_vector_type(2)))  int   i32x2;

static __device__ inline ushort f2bf(float x) {
    __hip_bfloat16 h = __float2bfloat16(x);
    ushort u;
    __builtin_memcpy(&u, &h, 2);
    return u;
}
static __device__ inline float bf2f(ushort u) {
    unsigned int v = ((unsigned int)u) << 16;
    float f;
    __builtin_memcpy(&f, &v, 4);
    return f;
}
static __device__ inline unsigned pack2bf(float lo, float hi) {
    return (unsigned)f2bf(lo) | ((unsigned)f2bf(hi) << 16);
}

#define GLDS16(g, l) __builtin_amdgcn_global_load_lds( \
    (const __attribute__((address_space(1))) void*)(g), \
    (__attribute__((address_space(3))) void*)(l), 16, 0, 0)

// ---------------- prep: convert_x + convert_w + concat_bias (fused) --------
__global__ __launch_bounds__(256)
void prep(const float* __restrict__ hs,
          const float* __restrict__ Wq, const float* __restrict__ Wk,
          const float* __restrict__ Wv, const float* __restrict__ Wo,
          const float* __restrict__ bq, const float* __restrict__ bk,
          const float* __restrict__ bv,
          ushort* __restrict__ Xbf, ushort* __restrict__ Wcat,
          ushort* __restrict__ Wot, float* __restrict__ bcat)
{
    __shared__ ushort T[64][65];
    const int bid = blockIdx.x;
    const int t   = threadIdx.x;

    if (bid < 3072) {                       // convert_x
        const int i = (bid * 256 + t) * 4;
        f32x4 v = *(const f32x4*)(hs + i);
        ushort4 o;
        o.x = f2bf(v[0]); o.y = f2bf(v[1]); o.z = f2bf(v[2]); o.w = f2bf(v[3]);
        *(ushort4*)(Xbf + i) = o;
    } else if (bid < 3072 + 576) {          // convert_w (transpose to [n][k])
        const int bid2 = bid - 3072;
        const int z = bid2 / 144;
        const int rem = bid2 % 144;
        const int n0 = (rem / 12) * 64;
        const int k0 = (rem % 12) * 64;
        const float* W = (z == 0) ? Wq : (z == 1) ? Wk : (z == 2) ? Wv : Wo;
        const int r = t >> 2, c0 = (t & 3) * 16;
        const float* src = W + (size_t)(k0 + r) * H_DIM + n0 + c0;
        #pragma unroll
        for (int j = 0; j < 16; j += 4) {
            f32x4 v = *(const f32x4*)(src + j);
            #pragma unroll
            for (int jj = 0; jj < 4; ++jj) T[r][c0 + j + jj] = f2bf(v[jj]);
        }
        __syncthreads();
        bf16x8 o0, o1;
        #pragma unroll
        for (int j = 0; j < 8; ++j) {
            o0[j] = (short)T[c0 + j][r];
            o1[j] = (short)T[c0 + 8 + j][r];
        }
        ushort* dst = (z < 3)
            ? Wcat + (size_t)(z * 768 + n0 + r) * H_DIM + k0 + c0
            : Wot  + (size_t)(n0 + r) * H_DIM + k0 + c0;
        *(bf16x8*)dst       = o0;
        *(bf16x8*)(dst + 8) = o1;
    } else {                                // concat_bias
        const int i = (bid - 3648) * 256 + t;
        if (i < NQKV) {
            float v = (i < 768) ? bq[i] : (i < 1536) ? bk[i - 768] : bv[i - 1536];
            bcat[i] = v;
        }
    }
}

// ---------------- MFMA GEMM: out[m][n] = A[m][:]·Bt[n][:] + bias (+resid) --
template<int OUTMODE>
__global__ __launch_bounds__(256)
void gemm_mfma(const ushort* __restrict__ A, const ushort* __restrict__ Bt,
               const float* __restrict__ bias, const float* __restrict__ resid,
               void* __restrict__ outp, ushort* __restrict__ vtp,
               int M, int N, int K, int nscale, float sfac)
{
    __shared__ ushort As[128 * 32];
    __shared__ ushort Bs[128 * 32];
    const int bn = blockIdx.x * 128;
    const int bm = blockIdx.y * 128;
    const int t  = threadIdx.x;
    const int w  = t >> 6, l = t & 63;
    const int lg = l >> 4, lr = l & 15;
    const int wr = w >> 1, wc = w & 1;

    f32x4 acc[4][4];
    #pragma unroll
    for (int i = 0; i < 4; ++i)
        #pragma unroll
        for (int j = 0; j < 4; ++j) acc[i][j] = (f32x4){0.f, 0.f, 0.f, 0.f};

    for (int k0 = 0; k0 < K; k0 += 32) {
        #pragma unroll
        for (int it = 0; it < 2; ++it) {
            const int g = it * 256 + t;
            const int r = g >> 2, cb = (g & 3) * 8;
            GLDS16(A  + (size_t)(bm + r) * K + k0 + cb, (char*)As + g * 16);
            GLDS16(Bt + (size_t)(bn + r) * K + k0 + cb, (char*)Bs + g * 16);
        }
        __syncthreads();
        bf16x8 af[4], bfr[4];
        #pragma unroll
        for (int m16 = 0; m16 < 4; ++m16)
            af[m16] = *(const bf16x8*)&As[(wr * 64 + m16 * 16 + lr) * 32 + lg * 8];
        #pragma unroll
        for (int n16 = 0; n16 < 4; ++n16)
            bfr[n16] = *(const bf16x8*)&Bs[(wc * 64 + n16 * 16 + lr) * 32 + lg * 8];
        #pragma unroll
        for (int m16 = 0; m16 < 4; ++m16)
            #pragma unroll
            for (int n16 = 0; n16 < 4; ++n16)
                acc[m16][n16] = __builtin_amdgcn_mfma_f32_16x16x32_bf16(
                    af[m16], bfr[n16], acc[m16][n16], 0, 0, 0);
        __syncthreads();
    }

    #pragma unroll
    for (int m16 = 0; m16 < 4; ++m16) {
        #pragma unroll
        for (int n16 = 0; n16 < 4; ++n16) {
            const int col = bn + wc * 64 + n16 * 16 + lr;
            const float bcol = bias[col];
            const int row0 = bm + wr * 64 + m16 * 16 + lg * 4;
            float vv[4];
            #pragma unroll
            for (int r = 0; r < 4; ++r) {
                float v = acc[m16][n16][r] + bcol;
                if (OUTMODE == 1) v += resid[(size_t)(row0 + r) * N + col];
                else if (col < nscale) v *= sfac;
                vv[r] = v;
            }
            if (OUTMODE == 1) {
                #pragma unroll
                for (int r = 0; r < 4; ++r)
                    ((float*)outp)[(size_t)(row0 + r) * N + col] = vv[r];
            } else if (col >= 1536) {
                const int dfull = col - 1536;
                const int hh = dfull >> 6, dd = dfull & 63;
                const int bb = row0 >> 11, ss = row0 & 2047;
                ushort4 pk;
                pk.x = f2bf(vv[0]); pk.y = f2bf(vv[1]);
                pk.z = f2bf(vv[2]); pk.w = f2bf(vv[3]);
                *(ushort4*)(vtp + ((size_t)(bb * NHEAD + hh) * HDIM + dd) * S_LEN + ss) = pk;
            } else {
                #pragma unroll
                for (int r = 0; r < 4; ++r)
                    ((ushort*)outp)[(size_t)(row0 + r) * N + col] = f2bf(vv[r]);
            }
        }
    }
}

// ---------------- MFMA flash attention: swapped-QK 32x32, kv-permuted PV ---
// S^T = mfma32x32(A=K, B=Q): lane holds P[q=lane&31][16 kv]; softmax is
// lane-local (no shuffles, no Ps LDS). PV uses a consistent kv-permutation
// so the lane's own packed quads ARE the A-fragment; V B-frags are 2x b64
// from swizzled Vs. K 3-buf / V 2-buf, counted vmcnt across raw s_barrier.
#define KT     64
#define ATT_QT 128
#define KVHALF (S_LEN / 2)
#define NTILES (KVHALF / KT)   // 16

__global__ __launch_bounds__(256, 3)
void attn_mfma(const ushort* __restrict__ Qbf, const ushort* __restrict__ Kbf,
               const ushort* __restrict__ Vt, const float* __restrict__ mask,
               ushort* __restrict__ Pp, float* __restrict__ lp)
{
    const int qt = blockIdx.x, h = blockIdx.y;
    const int b  = blockIdx.z >> 1, half = blockIdx.z & 1;
    const int t  = threadIdx.x;
    const int w  = t >> 6, l = t & 63;
    const int l31 = l & 31, hi = l >> 5;
    const int q0 = qt * ATT_QT;
    const int kb0 = half * KVHALF;

    __shared__ ushort Ks[3][KT][64];     // 24 KB, swizzled
    __shared__ ushort Vs[2][HDIM][64];   // 16 KB, swizzled ([d][kv])
    __shared__ float  kmarg[KVHALF];     //  4 KB: 0 valid / -1e30 masked

    {   // stage kv-mask args once
        const int i = t * 4;
        f32x4 v = *(const f32x4*)(mask + b * S_LEN + kb0 + i);
        #pragma unroll
        for (int j = 0; j < 4; ++j)
            kmarg[i + j] = (v[j] >= 0.f) ? 0.f : -1e30f;
    }

    const bool qnL = (mask[b * S_LEN + q0 + w * 32 + l31] < 0.f);

    // Q B-fragments: qa[k] = Q[q=l31][d = 16k + 8hi + j], j=0..7 (pre-scaled)
    bf16x8 qa[4];
    {
        const ushort* qsrc = Qbf + (size_t)(b * S_LEN + q0 + w * 32 + l31) * NQKV
                           + h * HDIM + 8 * hi;
        #pragma unroll
        for (int k = 0; k < 4; ++k)
            qa[k] = *(const bf16x8*)(qsrc + 16 * k);
    }

    // staging geometry (T2 swizzle: source column pre-swizzled, LDS linear)
    const int srow = w * 16 + (l >> 3);
    const int scol = ((l & 7) ^ (l >> 3)) * 8;
    const ushort* kLane = Kbf + (size_t)(b * S_LEN + kb0 + srow) * NQKV
                        + h * HDIM + scol;
    const ushort* vLane = Vt + ((size_t)(b * NHEAD + h) * HDIM + srow) * S_LEN
                        + kb0 + scol;
    char* ldsK = (char*)Ks + w * 2048 + l * 16;
    char* ldsV = (char*)Vs + w * 2048 + l * 16;

    __syncthreads();   // kmarg visible; vmem fully drained

    // prologue: K(0), V(0), K(1)
    GLDS16(kLane, ldsK);
    GLDS16(kLane + (size_t)8 * NQKV, ldsK + 1024);
    GLDS16(vLane, ldsV);
    GLDS16(vLane + (size_t)8 * S_LEN, ldsV + 1024);
    GLDS16(kLane + (size_t)KT * NQKV, ldsK + 8192);
    GLDS16(kLane + (size_t)(KT + 8) * NQKV, ldsK + 8192 + 1024);

    float l_part = 0.f;
    f32x16 accO[2];
    #pragma unroll
    for (int dt = 0; dt < 2; ++dt)
        #pragma unroll
        for (int i = 0; i < 16; ++i) accO[dt][i] = 0.f;

    const int swzl = (l31 & 7) << 4;

    for (int tt = 0; tt < NTILES; ++tt) {
        if (tt < NTILES - 1) {
            asm volatile("s_waitcnt vmcnt(2)" ::: "memory");
        } else {
            asm volatile("s_waitcnt vmcnt(0)" ::: "memory");
        }
        __builtin_amdgcn_s_barrier();

        if (tt + 1 < NTILES) {
            const ushort* vsrc = vLane + (size_t)(tt + 1) * KT;
            char* lv = ldsV + ((tt + 1) & 1) * 8192;
            GLDS16(vsrc, lv);
            GLDS16(vsrc + (size_t)8 * S_LEN, lv + 1024);
            if (tt + 2 < NTILES) {
                const ushort* ksrc = kLane + (size_t)(tt + 2) * KT * NQKV;
                char* lk = ldsK + ((tt + 2) % 3) * 8192;
                GLDS16(ksrc, lk);
                GLDS16(ksrc + (size_t)8 * NQKV, lk + 1024);
            }
        }

        const char* Kc = (const char*)Ks + (tt % 3) * 8192;
        const char* Vc = (const char*)Vs + (tt & 1) * 8192;

        #pragma unroll
        for (int kvt = 0; kvt < 2; ++kvt) {
            // ---- S^T[kv32][q32] = K · Q^T (scale folded into Q) ----
            f32x16 sc;
            __builtin_amdgcn_s_setprio(1);
            {
                const char* abase = Kc + (kvt * 32 + l31) * 128;
                bf16x8 a0 = *(const bf16x8*)(abase + ((16 * hi +  0) ^ swzl));
                bf16x8 a1 = *(const bf16x8*)(abase + ((16 * hi + 32) ^ swzl));
                bf16x8 a2 = *(const bf16x8*)(abase + ((16 * hi + 64) ^ swzl));
                bf16x8 a3 = *(const bf16x8*)(abase + ((16 * hi + 96) ^ swzl));
                f32x16 z;
                #pragma unroll
                for (int i = 0; i < 16; ++i) z[i] = 0.f;
                sc = __builtin_amdgcn_mfma_f32_32x32x16_bf16(a0, qa[0], z, 0, 0, 0);
                sc = __builtin_amdgcn_mfma_f32_32x32x16_bf16(a1, qa[1], sc, 0, 0, 0);
                sc = __builtin_amdgcn_mfma_f32_32x32x16_bf16(a2, qa[2], sc, 0, 0, 0);
                sc = __builtin_amdgcn_mfma_f32_32x32x16_bf16(a3, qa[3], sc, 0, 0, 0);
            }
            __builtin_amdgcn_s_setprio(0);

            // ---- lane-local softmax numerator: kv = 8*q4 + 4*hi + r ----
            float p[16];
            const float* km = &kmarg[tt * 64 + kvt * 32 + 4 * hi];
            #pragma unroll
            for (int q4 = 0; q4 < 4; ++q4) {
                f32x4 kq = *(const f32x4*)(km + 8 * q4);
                #pragma unroll
                for (int r = 0; r < 4; ++r) {
                    float arg = sc[q4 * 4 + r] + kq[r];
                    arg = qnL ? 0.f : arg;
                    const float pv = exp2f(arg);
                    p[q4 * 4 + r] = pv;
                    l_part += pv;
                }
            }

            // ---- pack own quads -> PV A-fragments (kv-permuted, no x-lane)
            __builtin_amdgcn_s_setprio(1);
            #pragma unroll
            for (int cc = 0; cc < 2; ++cc) {
                i32x4 pku;
                pku[0] = (int)pack2bf(p[8 * cc + 0], p[8 * cc + 1]);
                pku[1] = (int)pack2bf(p[8 * cc + 2], p[8 * cc + 3]);
                pku[2] = (int)pack2bf(p[8 * cc + 4], p[8 * cc + 5]);
                pku[3] = (int)pack2bf(p[8 * cc + 6], p[8 * cc + 7]);
                bf16x8 pa;
                __builtin_memcpy(&pa, &pku, 16);
                const int c = kvt * 2 + cc;   // kv chunk of 16 within tile
                #pragma unroll
                for (int dt = 0; dt < 2; ++dt) {
                    const char* vrow = Vc + (32 * dt + l31) * 128;
                    i32x2 v0 = *(const i32x2*)(vrow + ((32 * c + 8 * hi) ^ swzl));
                    i32x2 v1 = *(const i32x2*)(vrow + ((32 * c + 16 + 8 * hi) ^ swzl));
                    i32x4 vv;
                    vv[0] = v0[0]; vv[1] = v0[1]; vv[2] = v1[0]; vv[3] = v1[1];
                    bf16x8 bv;
                    __builtin_memcpy(&bv, &vv, 16);
                    accO[dt] = __builtin_amdgcn_mfma_f32_32x32x16_bf16(
                        pa, bv, accO[dt], 0, 0, 0);
                }
            }
            __builtin_amdgcn_s_setprio(0);
        }
    }

    // full denominator for q = l31: sum the two lane-halves
    l_part += __shfl_xor(l_part, 32, 64);

    // write unnormalized partial O (bf16) + l (f32)
    const size_t MN = (size_t)M_TOT * H_DIM;
    #pragma unroll
    for (int dt = 0; dt < 2; ++dt) {
        #pragma unroll
        for (int reg = 0; reg < 16; ++reg) {
            const int q = (reg & 3) + 8 * (reg >> 2) + 4 * hi;
            const int m = b * S_LEN + q0 + w * 32 + q;
            Pp[(size_t)half * MN + (size_t)m * H_DIM + h * HDIM + 32 * dt + l31]
                = f2bf(accO[dt][reg]);
        }
    }
    if (hi == 0) {
        const int m = b * S_LEN + q0 + w * 32 + l31;
        lp[half * (M_TOT * NHEAD) + m * NHEAD + h] = l_part;
    }
}

// ---------------- combine: ctx = (P0+P1)/(l0+l1) ---------------------------
__global__ __launch_bounds__(256)
void combine_kernel(const ushort* __restrict__ Pp, const float* __restrict__ lp,
                    ushort* __restrict__ ctx)
{
    const int idx = blockIdx.x * 256 + threadIdx.x;   // over M_TOT*96
    const int m  = idx / 96;
    const int c8 = idx % 96;
    const int c  = c8 * 8;
    const int h  = c8 >> 3;
    const size_t MN = (size_t)M_TOT * H_DIM;

    const float lsum = lp[m * NHEAD + h] + lp[M_TOT * NHEAD + m * NHEAD + h];
    const float inv  = 1.0f / lsum;

    bf16x8 a = *(const bf16x8*)(Pp + (size_t)m * H_DIM + c);
    bf16x8 b = *(const bf16x8*)(Pp + MN + (size_t)m * H_DIM + c);
    bf16x8 o;
    #pragma unroll
    for (int j = 0; j < 8; ++j)
        o[j] = (short)f2bf((bf2f((ushort)a[j]) + bf2f((ushort)b[j])) * inv);
    *(bf16x8*)(ctx + (size_t)m * H_DIM + c) = o;
}

// ---------------- LayerNorm (wave-per-row, shuffle reduce, no LDS) ---------
__global__ __launch_bounds__(256)
void ln_kernel(const float* __restrict__ Hbuf, const float* __restrict__ gamma,
               const float* __restrict__ beta, float* __restrict__ out)
{
    const int m = blockIdx.x * 4 + (threadIdx.x >> 6);
    const int l = threadIdx.x & 63;
    const float* row = Hbuf + (size_t)m * H_DIM;

    f32x4 x[3];
    #pragma unroll
    for (int k = 0; k < 3; ++k) x[k] = *(const f32x4*)(row + l * 4 + k * 256);

    float s = 0.f;
    #pragma unroll
    for (int k = 0; k < 3; ++k)
        #pragma unroll
        for (int j = 0; j < 4; ++j) s += x[k][j];
    #pragma unroll
    for (int off = 1; off < 64; off <<= 1) s += __shfl_xor(s, off, 64);
    const float mu = s * (1.0f / H_DIM);

    float v = 0.f;
    #pragma unroll
    for (int k = 0; k < 3; ++k)
        #pragma unroll
        for (int j = 0; j < 4; ++j) {
            const float d = x[k][j] - mu;
            v += d * d;
        }
    #pragma unroll
    for (int off = 1; off < 64; off <<= 1) v += __shfl_xor(v, off, 64);
    const float rstd = rsqrtf(v * (1.0f / H_DIM) + LN_EPS);

    #pragma unroll
    for (int k = 0; k < 3; ++k) {
        const int c = l * 4 + k * 256;
        f32x4 gm = *(const f32x4*)(gamma + c);
        f32x4 bt = *(const f32x4*)(beta + c);
        f32x4 o;
        #pragma unroll
        for (int j = 0; j < 4; ++j)
            o[j] = (x[k][j] - mu) * rstd * gm[j] + bt[j];
        *(f32x4*)(out + (size_t)m * H_DIM + c) = o;
    }
}

// ---------------------------------------------------------------------------
extern "C" void kernel_launch(void* const* d_in, const int* in_sizes, int n_in,
                              void* d_out, int out_size, void* d_ws, size_t ws_size,
                              hipStream_t stream)
{
    const float* hs   = (const float*)d_in[0];
    const float* mask = (const float*)d_in[1];
    const float* Wq   = (const float*)d_in[2];
    const float* bq   = (const float*)d_in[3];
    const float* Wk   = (const float*)d_in[4];
    const float* bk   = (const float*)d_in[5];
    const float* Wv   = (const float*)d_in[6];
    const float* bv   = (const float*)d_in[7];
    const float* Wo   = (const float*)d_in[8];
    const float* bo   = (const float*)d_in[9];
    const float* g    = (const float*)d_in[10];
    const float* be   = (const float*)d_in[11];
    float* out = (float*)d_out;

    char* base = (char*)d_ws;
    ushort* Xbf    = (ushort*)(base);                    //  6,291,456 B
    ushort* QKVbf  = (ushort*)(base + 6291456);          // 18,874,368 B
    ushort* Wcat   = (ushort*)(base + 25165824);         //  3,538,944 B (lp after QKV gemm)
    ushort* Wot    = (ushort*)(base + 28704768);         //  1,179,648 B
    float*  bcat   = (float*) (base + 29884416);         //      9,216 B
    ushort* Vt     = (ushort*)(base + 29893632);         //  6,291,456 B
    ushort* Cbf    = (ushort*)(base + 36185088);         //  6,291,456 B
    float*  Hb     = (float*) (base + 42476544);         // 12,582,912 B (Pp before out-GEMM)
    float*  lp     = (float*) (base + 25165824);         // reuse Wcat region
    ushort* Pp     = (ushort*)(base + 42476544);         // reuse Hb region

    prep<<<3657, 256, 0, stream>>>(hs, Wq, Wk, Wv, Wo, bq, bk, bv,
                                   Xbf, Wcat, Wot, bcat);

    // Q cols (<768) pre-scaled by SM_C; V cols (>=1536) fused-transposed to Vt
    gemm_mfma<0><<<dim3(NQKV / 128, M_TOT / 128), 256, 0, stream>>>(
        Xbf, Wcat, bcat, nullptr, QKVbf, Vt, M_TOT, NQKV, H_DIM, 768, SM_C);

    attn_mfma<<<dim3(S_LEN / ATT_QT, NHEAD, B_SZ * 2), 256, 0, stream>>>(
        QKVbf, QKVbf + 768, Vt, mask, Pp, lp);

    combine_kernel<<<M_TOT * 96 / 256, 256, 0, stream>>>(Pp, lp, Cbf);

    gemm_mfma<1><<<dim3(H_DIM / 128, M_TOT / 128), 256, 0, stream>>>(
        Cbf, Wot, bo, hs, Hb, nullptr, M_TOT, H_DIM, H_DIM, 0, 1.0f);

    ln_kernel<<<M_TOT / 4, 256, 0, stream>>>(Hb, g, be, out);
}

// Round 11
// 123.339 us; speedup vs baseline: 1.5082x; 1.0184x over previous
//
#include <hip/hip_runtime.h>
#include <hip/hip_bf16.h>

#define H_DIM 768
#define NHEAD 12
#define HDIM  64
#define S_LEN 2048
#define B_SZ  2
#define M_TOT (B_SZ * S_LEN)   // 4096
#define NQKV  (3 * H_DIM)      // 2304
#define LN_EPS 1e-5f
#define SM_C   0.1803368801f   // 0.125 * log2(e)

typedef __attribute__((ext_vector_type(8)))  short bf16x8;
typedef __attribute__((ext_vector_type(4)))  float f32x4;
typedef __attribute__((ext_vector_type(16))) float f32x16;
typedef __attribute__((ext_vector_type(4)))  int   i32x4;

static __device__ inline ushort f2bf(float x) {
    __hip_bfloat16 h = __float2bfloat16(x);
    ushort u;
    __builtin_memcpy(&u, &h, 2);
    return u;
}
static __device__ inline float bf2f(ushort u) {
    unsigned int v = ((unsigned int)u) << 16;
    float f;
    __builtin_memcpy(&f, &v, 4);
    return f;
}
static __device__ inline unsigned pack2bf(float lo, float hi) {
    return (unsigned)f2bf(lo) | ((unsigned)f2bf(hi) << 16);
}

#define GLDS16(g, l) __builtin_amdgcn_global_load_lds( \
    (const __attribute__((address_space(1))) void*)(g), \
    (__attribute__((address_space(3))) void*)(l), 16, 0, 0)

// ---------------- prep: convert_x + convert_w + concat_bias (fused) --------
__global__ __launch_bounds__(256)
void prep(const float* __restrict__ hs,
          const float* __restrict__ Wq, const float* __restrict__ Wk,
          const float* __restrict__ Wv, const float* __restrict__ Wo,
          const float* __restrict__ bq, const float* __restrict__ bk,
          const float* __restrict__ bv,
          ushort* __restrict__ Xbf, ushort* __restrict__ Wcat,
          ushort* __restrict__ Wot, float* __restrict__ bcat)
{
    __shared__ ushort T[64][65];
    const int bid = blockIdx.x;
    const int t   = threadIdx.x;

    if (bid < 3072) {                       // convert_x
        const int i = (bid * 256 + t) * 4;
        f32x4 v = *(const f32x4*)(hs + i);
        ushort4 o;
        o.x = f2bf(v[0]); o.y = f2bf(v[1]); o.z = f2bf(v[2]); o.w = f2bf(v[3]);
        *(ushort4*)(Xbf + i) = o;
    } else if (bid < 3072 + 576) {          // convert_w (transpose to [n][k])
        const int bid2 = bid - 3072;
        const int z = bid2 / 144;
        const int rem = bid2 % 144;
        const int n0 = (rem / 12) * 64;
        const int k0 = (rem % 12) * 64;
        const float* W = (z == 0) ? Wq : (z == 1) ? Wk : (z == 2) ? Wv : Wo;
        const int r = t >> 2, c0 = (t & 3) * 16;
        const float* src = W + (size_t)(k0 + r) * H_DIM + n0 + c0;
        #pragma unroll
        for (int j = 0; j < 16; j += 4) {
            f32x4 v = *(const f32x4*)(src + j);
            #pragma unroll
            for (int jj = 0; jj < 4; ++jj) T[r][c0 + j + jj] = f2bf(v[jj]);
        }
        __syncthreads();
        bf16x8 o0, o1;
        #pragma unroll
        for (int j = 0; j < 8; ++j) {
            o0[j] = (short)T[c0 + j][r];
            o1[j] = (short)T[c0 + 8 + j][r];
        }
        ushort* dst = (z < 3)
            ? Wcat + (size_t)(z * 768 + n0 + r) * H_DIM + k0 + c0
            : Wot  + (size_t)(n0 + r) * H_DIM + k0 + c0;
        *(bf16x8*)dst       = o0;
        *(bf16x8*)(dst + 8) = o1;
    } else {                                // concat_bias
        const int i = (bid - 3648) * 256 + t;
        if (i < NQKV) {
            float v = (i < 768) ? bq[i] : (i < 1536) ? bk[i - 768] : bv[i - 1536];
            bcat[i] = v;
        }
    }
}

// ---------------- MFMA GEMM: out[m][n] = A[m][:]·Bt[n][:] + bias (+resid) --
template<int OUTMODE>
__global__ __launch_bounds__(256)
void gemm_mfma(const ushort* __restrict__ A, const ushort* __restrict__ Bt,
               const float* __restrict__ bias, const float* __restrict__ resid,
               void* __restrict__ outp, ushort* __restrict__ vtp,
               int M, int N, int K, int nscale, float sfac)
{
    __shared__ ushort As[128 * 32];
    __shared__ ushort Bs[128 * 32];
    const int bn = blockIdx.x * 128;
    const int bm = blockIdx.y * 128;
    const int t  = threadIdx.x;
    const int w  = t >> 6, l = t & 63;
    const int lg = l >> 4, lr = l & 15;
    const int wr = w >> 1, wc = w & 1;

    f32x4 acc[4][4];
    #pragma unroll
    for (int i = 0; i < 4; ++i)
        #pragma unroll
        for (int j = 0; j < 4; ++j) acc[i][j] = (f32x4){0.f, 0.f, 0.f, 0.f};

    for (int k0 = 0; k0 < K; k0 += 32) {
        #pragma unroll
        for (int it = 0; it < 2; ++it) {
            const int g = it * 256 + t;
            const int r = g >> 2, cb = (g & 3) * 8;
            GLDS16(A  + (size_t)(bm + r) * K + k0 + cb, (char*)As + g * 16);
            GLDS16(Bt + (size_t)(bn + r) * K + k0 + cb, (char*)Bs + g * 16);
        }
        __syncthreads();
        bf16x8 af[4], bfr[4];
        #pragma unroll
        for (int m16 = 0; m16 < 4; ++m16)
            af[m16] = *(const bf16x8*)&As[(wr * 64 + m16 * 16 + lr) * 32 + lg * 8];
        #pragma unroll
        for (int n16 = 0; n16 < 4; ++n16)
            bfr[n16] = *(const bf16x8*)&Bs[(wc * 64 + n16 * 16 + lr) * 32 + lg * 8];
        #pragma unroll
        for (int m16 = 0; m16 < 4; ++m16)
            #pragma unroll
            for (int n16 = 0; n16 < 4; ++n16)
                acc[m16][n16] = __builtin_amdgcn_mfma_f32_16x16x32_bf16(
                    af[m16], bfr[n16], acc[m16][n16], 0, 0, 0);
        __syncthreads();
    }

    #pragma unroll
    for (int m16 = 0; m16 < 4; ++m16) {
        #pragma unroll
        for (int n16 = 0; n16 < 4; ++n16) {
            const int col = bn + wc * 64 + n16 * 16 + lr;
            const float bcol = bias[col];
            const int row0 = bm + wr * 64 + m16 * 16 + lg * 4;
            float vv[4];
            #pragma unroll
            for (int r = 0; r < 4; ++r) {
                float v = acc[m16][n16][r] + bcol;
                if (OUTMODE == 1) v += resid[(size_t)(row0 + r) * N + col];
                else if (col < nscale) v *= sfac;
                vv[r] = v;
            }
            if (OUTMODE == 1) {
                #pragma unroll
                for (int r = 0; r < 4; ++r)
                    ((float*)outp)[(size_t)(row0 + r) * N + col] = vv[r];
            } else if (col >= 1536) {
                const int dfull = col - 1536;
                const int hh = dfull >> 6, dd = dfull & 63;
                const int bb = row0 >> 11, ss = row0 & 2047;
                ushort4 pk;
                pk.x = f2bf(vv[0]); pk.y = f2bf(vv[1]);
                pk.z = f2bf(vv[2]); pk.w = f2bf(vv[3]);
                *(ushort4*)(vtp + ((size_t)(bb * NHEAD + hh) * HDIM + dd) * S_LEN + ss) = pk;
            } else {
                #pragma unroll
                for (int r = 0; r < 4; ++r)
                    ((ushort*)outp)[(size_t)(row0 + r) * N + col] = f2bf(vv[r]);
            }
        }
    }
}

// ---------------- MFMA flash attention: swapped-QK 32x32, sigma-staged K ---
// K is staged with row permutation sigma (swap row-quads 1<->2 per 16) so the
// S^T output registers hold kv in PV A-fragment order -> PV B-frags are
// single b128 reads (conflict-free, same pattern as K's QK reads).
// K 3-buf / V 2-buf, counted vmcnt across raw s_barrier. XCD-chunked grid.
#define KT     64
#define ATT_QT 128
#define KVHALF (S_LEN / 2)
#define NTILES (KVHALF / KT)   // 16

__global__ __launch_bounds__(256, 3)
void attn_mfma(const ushort* __restrict__ Qbf, const ushort* __restrict__ Kbf,
               const ushort* __restrict__ Vt, const float* __restrict__ mask,
               ushort* __restrict__ Pp, float* __restrict__ lp)
{
    // XCD chunking: HW round-robins flat id % 8; give each XCD the 96
    // consecutive works = 6 full (h,b,half) combos (all 16 qt together).
    const int flat = blockIdx.x;
    const int wk   = (flat & 7) * 96 + (flat >> 3);
    const int qt   = wk & 15;
    const int c_   = wk >> 4;            // 0..47 = bz*12 + h
    const int h    = c_ % 12;
    const int bz   = c_ / 12;
    const int b    = bz >> 1, half = bz & 1;

    const int t  = threadIdx.x;
    const int w  = t >> 6, l = t & 63;
    const int l31 = l & 31, hi = l >> 5;
    const int q0 = qt * ATT_QT;
    const int kb0 = half * KVHALF;

    __shared__ ushort Ks[3][KT][64];     // 24 KB, swizzled, sigma-row-permuted
    __shared__ ushort Vs[2][HDIM][64];   // 16 KB, swizzled ([d][kv])
    __shared__ float  kmarg[KVHALF];     //  4 KB: 0 valid / -1e30 masked

    {   // stage kv-mask args once
        const int i = t * 4;
        f32x4 v = *(const f32x4*)(mask + b * S_LEN + kb0 + i);
        #pragma unroll
        for (int j = 0; j < 4; ++j)
            kmarg[i + j] = (v[j] >= 0.f) ? 0.f : -1e30f;
    }

    const bool qnL = (mask[b * S_LEN + q0 + w * 32 + l31] < 0.f);

    // Q B-fragments: qa[k] = Q[q=l31][d = 16k + 8hi + j] (pre-scaled by SM_C)
    bf16x8 qa[4];
    {
        const ushort* qsrc = Qbf + (size_t)(b * S_LEN + q0 + w * 32 + l31) * NQKV
                           + h * HDIM + 8 * hi;
        #pragma unroll
        for (int k = 0; k < 4; ++k)
            qa[k] = *(const bf16x8*)(qsrc + 16 * k);
    }

    // staging geometry (T2 swizzle: source column pre-swizzled, LDS linear)
    const int u    = l >> 3;                    // 0..7
    const int scol = ((l & 7) ^ u) * 8;
    // sigma: LDS rows {w*16+u, w*16+u+8} take K rows {srcK, srcK+4}
    const int srcK = w * 16 + u + ((u & 4) ? 4 : 0);
    const int srow = w * 16 + u;                // V rows unpermuted
    const ushort* kLane = Kbf + (size_t)(b * S_LEN + kb0 + srcK) * NQKV
                        + h * HDIM + scol;
    const ushort* vLane = Vt + ((size_t)(b * NHEAD + h) * HDIM + srow) * S_LEN
                        + kb0 + scol;
    char* ldsK = (char*)Ks + w * 2048 + l * 16;
    char* ldsV = (char*)Vs + w * 2048 + l * 16;

    __syncthreads();   // kmarg visible; vmem fully drained

    // prologue: K(0), V(0), K(1)
    GLDS16(kLane, ldsK);
    GLDS16(kLane + (size_t)4 * NQKV, ldsK + 1024);
    GLDS16(vLane, ldsV);
    GLDS16(vLane + (size_t)8 * S_LEN, ldsV + 1024);
    GLDS16(kLane + (size_t)KT * NQKV, ldsK + 8192);
    GLDS16(kLane + (size_t)(KT + 4) * NQKV, ldsK + 8192 + 1024);

    float l_part = 0.f;
    f32x16 accO[2];
    #pragma unroll
    for (int dt = 0; dt < 2; ++dt)
        #pragma unroll
        for (int i = 0; i < 16; ++i) accO[dt][i] = 0.f;

    const int swzl = (l31 & 7) << 4;

    for (int tt = 0; tt < NTILES; ++tt) {
        if (tt < NTILES - 1) {
            asm volatile("s_waitcnt vmcnt(2)" ::: "memory");
        } else {
            asm volatile("s_waitcnt vmcnt(0)" ::: "memory");
        }
        __builtin_amdgcn_s_barrier();

        if (tt + 1 < NTILES) {
            const ushort* vsrc = vLane + (size_t)(tt + 1) * KT;
            char* lv = ldsV + ((tt + 1) & 1) * 8192;
            GLDS16(vsrc, lv);
            GLDS16(vsrc + (size_t)8 * S_LEN, lv + 1024);
            if (tt + 2 < NTILES) {
                const ushort* ksrc = kLane + (size_t)(tt + 2) * KT * NQKV;
                char* lk = ldsK + ((tt + 2) % 3) * 8192;
                GLDS16(ksrc, lk);
                GLDS16(ksrc + (size_t)4 * NQKV, lk + 1024);
            }
        }

        const char* Kc = (const char*)Ks + (tt % 3) * 8192;
        const char* Vc = (const char*)Vs + (tt & 1) * 8192;

        #pragma unroll
        for (int kvt = 0; kvt < 2; ++kvt) {
            // ---- S^T = K · Q^T (sigma-permuted LDS rows; scale in Q) ----
            f32x16 sc;
            __builtin_amdgcn_s_setprio(1);
            {
                const char* abase = Kc + (kvt * 32 + l31) * 128;
                bf16x8 a0 = *(const bf16x8*)(abase + ((16 * hi +  0) ^ swzl));
                bf16x8 a1 = *(const bf16x8*)(abase + ((16 * hi + 32) ^ swzl));
                bf16x8 a2 = *(const bf16x8*)(abase + ((16 * hi + 64) ^ swzl));
                bf16x8 a3 = *(const bf16x8*)(abase + ((16 * hi + 96) ^ swzl));
                f32x16 z;
                #pragma unroll
                for (int i = 0; i < 16; ++i) z[i] = 0.f;
                sc = __builtin_amdgcn_mfma_f32_32x32x16_bf16(a0, qa[0], z, 0, 0, 0);
                sc = __builtin_amdgcn_mfma_f32_32x32x16_bf16(a1, qa[1], sc, 0, 0, 0);
                sc = __builtin_amdgcn_mfma_f32_32x32x16_bf16(a2, qa[2], sc, 0, 0, 0);
                sc = __builtin_amdgcn_mfma_f32_32x32x16_bf16(a3, qa[3], sc, 0, 0, 0);
            }
            __builtin_amdgcn_s_setprio(0);

            // ---- lane-local softmax: reg q4*4+r <-> logical kv =
            //      16*(q4>>1) + 8*hi + 4*(q4&1) + r  (sigma mapping) ----
            float p[16];
            const float* km = &kmarg[tt * 64 + kvt * 32];
            #pragma unroll
            for (int q4 = 0; q4 < 4; ++q4) {
                const int kvb = 16 * (q4 >> 1) + 8 * hi + 4 * (q4 & 1);
                f32x4 kq = *(const f32x4*)(km + kvb);
                #pragma unroll
                for (int r = 0; r < 4; ++r) {
                    float arg = sc[q4 * 4 + r] + kq[r];
                    arg = qnL ? 0.f : arg;
                    const float pv = exp2f(arg);
                    p[q4 * 4 + r] = pv;
                    l_part += pv;
                }
            }

            // ---- PV: A-frag = p[0..7]/p[8..15] in order; B-frag = b128 ----
            __builtin_amdgcn_s_setprio(1);
            #pragma unroll
            for (int cc = 0; cc < 2; ++cc) {
                i32x4 pku;
                pku[0] = (int)pack2bf(p[8 * cc + 0], p[8 * cc + 1]);
                pku[1] = (int)pack2bf(p[8 * cc + 2], p[8 * cc + 3]);
                pku[2] = (int)pack2bf(p[8 * cc + 4], p[8 * cc + 5]);
                pku[3] = (int)pack2bf(p[8 * cc + 6], p[8 * cc + 7]);
                bf16x8 pa;
                __builtin_memcpy(&pa, &pku, 16);
                const int c = kvt * 2 + cc;   // kv chunk of 16 within tile
                #pragma unroll
                for (int dt = 0; dt < 2; ++dt) {
                    bf16x8 bv = *(const bf16x8*)(Vc + (32 * dt + l31) * 128
                                                 + ((32 * c + 16 * hi) ^ swzl));
                    accO[dt] = __builtin_amdgcn_mfma_f32_32x32x16_bf16(
                        pa, bv, accO[dt], 0, 0, 0);
                }
            }
            __builtin_amdgcn_s_setprio(0);
        }
    }

    // full denominator for q = l31: sum the two lane-halves
    l_part += __shfl_xor(l_part, 32, 64);

    // write unnormalized partial O (bf16) + l (f32)
    const size_t MN = (size_t)M_TOT * H_DIM;
    #pragma unroll
    for (int dt = 0; dt < 2; ++dt) {
        #pragma unroll
        for (int reg = 0; reg < 16; ++reg) {
            const int q = (reg & 3) + 8 * (reg >> 2) + 4 * hi;
            const int m = b * S_LEN + q0 + w * 32 + q;
            Pp[(size_t)half * MN + (size_t)m * H_DIM + h * HDIM + 32 * dt + l31]
                = f2bf(accO[dt][reg]);
        }
    }
    if (hi == 0) {
        const int m = b * S_LEN + q0 + w * 32 + l31;
        lp[half * (M_TOT * NHEAD) + m * NHEAD + h] = l_part;
    }
}

// ---------------- combine: ctx = (P0+P1)/(l0+l1) ---------------------------
__global__ __launch_bounds__(256)
void combine_kernel(const ushort* __restrict__ Pp, const float* __restrict__ lp,
                    ushort* __restrict__ ctx)
{
    const int idx = blockIdx.x * 256 + threadIdx.x;   // over M_TOT*96
    const int m  = idx / 96;
    const int c8 = idx % 96;
    const int c  = c8 * 8;
    const int h  = c8 >> 3;
    const size_t MN = (size_t)M_TOT * H_DIM;

    const float lsum = lp[m * NHEAD + h] + lp[M_TOT * NHEAD + m * NHEAD + h];
    const float inv  = 1.0f / lsum;

    bf16x8 a = *(const bf16x8*)(Pp + (size_t)m * H_DIM + c);
    bf16x8 b = *(const bf16x8*)(Pp + MN + (size_t)m * H_DIM + c);
    bf16x8 o;
    #pragma unroll
    for (int j = 0; j < 8; ++j)
        o[j] = (short)f2bf((bf2f((ushort)a[j]) + bf2f((ushort)b[j])) * inv);
    *(bf16x8*)(ctx + (size_t)m * H_DIM + c) = o;
}

// ---------------- LayerNorm (wave-per-row, shuffle reduce, no LDS) ---------
__global__ __launch_bounds__(256)
void ln_kernel(const float* __restrict__ Hbuf, const float* __restrict__ gamma,
               const float* __restrict__ beta, float* __restrict__ out)
{
    const int m = blockIdx.x * 4 + (threadIdx.x >> 6);
    const int l = threadIdx.x & 63;
    const float* row = Hbuf + (size_t)m * H_DIM;

    f32x4 x[3];
    #pragma unroll
    for (int k = 0; k < 3; ++k) x[k] = *(const f32x4*)(row + l * 4 + k * 256);

    float s = 0.f;
    #pragma unroll
    for (int k = 0; k < 3; ++k)
        #pragma unroll
        for (int j = 0; j < 4; ++j) s += x[k][j];
    #pragma unroll
    for (int off = 1; off < 64; off <<= 1) s += __shfl_xor(s, off, 64);
    const float mu = s * (1.0f / H_DIM);

    float v = 0.f;
    #pragma unroll
    for (int k = 0; k < 3; ++k)
        #pragma unroll
        for (int j = 0; j < 4; ++j) {
            const float d = x[k][j] - mu;
            v += d * d;
        }
    #pragma unroll
    for (int off = 1; off < 64; off <<= 1) v += __shfl_xor(v, off, 64);
    const float rstd = rsqrtf(v * (1.0f / H_DIM) + LN_EPS);

    #pragma unroll
    for (int k = 0; k < 3; ++k) {
        const int c = l * 4 + k * 256;
        f32x4 gm = *(const f32x4*)(gamma + c);
        f32x4 bt = *(const f32x4*)(beta + c);
        f32x4 o;
        #pragma unroll
        for (int j = 0; j < 4; ++j)
            o[j] = (x[k][j] - mu) * rstd * gm[j] + bt[j];
        *(f32x4*)(out + (size_t)m * H_DIM + c) = o;
    }
}

// ---------------------------------------------------------------------------
extern "C" void kernel_launch(void* const* d_in, const int* in_sizes, int n_in,
                              void* d_out, int out_size, void* d_ws, size_t ws_size,
                              hipStream_t stream)
{
    const float* hs   = (const float*)d_in[0];
    const float* mask = (const float*)d_in[1];
    const float* Wq   = (const float*)d_in[2];
    const float* bq   = (const float*)d_in[3];
    const float* Wk   = (const float*)d_in[4];
    const float* bk   = (const float*)d_in[5];
    const float* Wv   = (const float*)d_in[6];
    const float* bv   = (const float*)d_in[7];
    const float* Wo   = (const float*)d_in[8];
    const float* bo   = (const float*)d_in[9];
    const float* g    = (const float*)d_in[10];
    const float* be   = (const float*)d_in[11];
    float* out = (float*)d_out;

    char* base = (char*)d_ws;
    ushort* Xbf    = (ushort*)(base);                    //  6,291,456 B
    ushort* QKVbf  = (ushort*)(base + 6291456);          // 18,874,368 B
    ushort* Wcat   = (ushort*)(base + 25165824);         //  3,538,944 B (lp after QKV gemm)
    ushort* Wot    = (ushort*)(base + 28704768);         //  1,179,648 B
    float*  bcat   = (float*) (base + 29884416);         //      9,216 B
    ushort* Vt     = (ushort*)(base + 29893632);         //  6,291,456 B
    ushort* Cbf    = (ushort*)(base + 36185088);         //  6,291,456 B
    float*  Hb     = (float*) (base + 42476544);         // 12,582,912 B (Pp before out-GEMM)
    float*  lp     = (float*) (base + 25165824);         // reuse Wcat region
    ushort* Pp     = (ushort*)(base + 42476544);         // reuse Hb region

    prep<<<3657, 256, 0, stream>>>(hs, Wq, Wk, Wv, Wo, bq, bk, bv,
                                   Xbf, Wcat, Wot, bcat);

    // Q cols (<768) pre-scaled by SM_C; V cols (>=1536) fused-transposed to Vt
    gemm_mfma<0><<<dim3(NQKV / 128, M_TOT / 128), 256, 0, stream>>>(
        Xbf, Wcat, bcat, nullptr, QKVbf, Vt, M_TOT, NQKV, H_DIM, 768, SM_C);

    attn_mfma<<<768, 256, 0, stream>>>(
        QKVbf, QKVbf + 768, Vt, mask, Pp, lp);

    combine_kernel<<<M_TOT * 96 / 256, 256, 0, stream>>>(Pp, lp, Cbf);

    gemm_mfma<1><<<dim3(H_DIM / 128, M_TOT / 128), 256, 0, stream>>>(
        Cbf, Wot, bo, hs, Hb, nullptr, M_TOT, H_DIM, H_DIM, 0, 1.0f);

    ln_kernel<<<M_TOT / 4, 256, 0, stream>>>(Hb, g, be, out);
}

// Round 12
// 120.017 us; speedup vs baseline: 1.5500x; 1.0277x over previous
//
#include <hip/hip_runtime.h>
#include <hip/hip_bf16.h>

#define H_DIM 768
#define NHEAD 12
#define HDIM  64
#define S_LEN 2048
#define B_SZ  2
#define M_TOT (B_SZ * S_LEN)   // 4096
#define NQKV  (3 * H_DIM)      // 2304
#define LN_EPS 1e-5f
#define SM_C   0.1803368801f   // 0.125 * log2(e)

typedef __attribute__((ext_vector_type(8)))  short bf16x8;
typedef __attribute__((ext_vector_type(4)))  float f32x4;
typedef __attribute__((ext_vector_type(16))) float f32x16;
typedef __attribute__((ext_vector_type(4)))  int   i32x4;

static __device__ inline ushort f2bf(float x) {
    __hip_bfloat16 h = __float2bfloat16(x);
    ushort u;
    __builtin_memcpy(&u, &h, 2);
    return u;
}
static __device__ inline float bf2f(ushort u) {
    unsigned int v = ((unsigned int)u) << 16;
    float f;
    __builtin_memcpy(&f, &v, 4);
    return f;
}
// hardware packed f32->bf16 convert (RTNE), 1 instruction for 2 values
static __device__ inline unsigned cvt_pk_bf16(float lo, float hi) {
    unsigned r;
    asm("v_cvt_pk_bf16_f32 %0, %1, %2" : "=v"(r) : "v"(lo), "v"(hi));
    return r;
}

#define GLDS16(g, l) __builtin_amdgcn_global_load_lds( \
    (const __attribute__((address_space(1))) void*)(g), \
    (__attribute__((address_space(3))) void*)(l), 16, 0, 0)

// ---------------- prep: convert_x + convert_w + concat_bias (fused) --------
__global__ __launch_bounds__(256)
void prep(const float* __restrict__ hs,
          const float* __restrict__ Wq, const float* __restrict__ Wk,
          const float* __restrict__ Wv, const float* __restrict__ Wo,
          const float* __restrict__ bq, const float* __restrict__ bk,
          const float* __restrict__ bv,
          ushort* __restrict__ Xbf, ushort* __restrict__ Wcat,
          ushort* __restrict__ Wot, float* __restrict__ bcat)
{
    __shared__ ushort T[64][65];
    const int bid = blockIdx.x;
    const int t   = threadIdx.x;

    if (bid < 3072) {                       // convert_x
        const int i = (bid * 256 + t) * 4;
        f32x4 v = *(const f32x4*)(hs + i);
        ushort4 o;
        o.x = f2bf(v[0]); o.y = f2bf(v[1]); o.z = f2bf(v[2]); o.w = f2bf(v[3]);
        *(ushort4*)(Xbf + i) = o;
    } else if (bid < 3072 + 576) {          // convert_w (transpose to [n][k])
        const int bid2 = bid - 3072;
        const int z = bid2 / 144;
        const int rem = bid2 % 144;
        const int n0 = (rem / 12) * 64;
        const int k0 = (rem % 12) * 64;
        const float* W = (z == 0) ? Wq : (z == 1) ? Wk : (z == 2) ? Wv : Wo;
        const int r = t >> 2, c0 = (t & 3) * 16;
        const float* src = W + (size_t)(k0 + r) * H_DIM + n0 + c0;
        #pragma unroll
        for (int j = 0; j < 16; j += 4) {
            f32x4 v = *(const f32x4*)(src + j);
            #pragma unroll
            for (int jj = 0; jj < 4; ++jj) T[r][c0 + j + jj] = f2bf(v[jj]);
        }
        __syncthreads();
        bf16x8 o0, o1;
        #pragma unroll
        for (int j = 0; j < 8; ++j) {
            o0[j] = (short)T[c0 + j][r];
            o1[j] = (short)T[c0 + 8 + j][r];
        }
        ushort* dst = (z < 3)
            ? Wcat + (size_t)(z * 768 + n0 + r) * H_DIM + k0 + c0
            : Wot  + (size_t)(n0 + r) * H_DIM + k0 + c0;
        *(bf16x8*)dst       = o0;
        *(bf16x8*)(dst + 8) = o1;
    } else {                                // concat_bias
        const int i = (bid - 3648) * 256 + t;
        if (i < NQKV) {
            float v = (i < 768) ? bq[i] : (i < 1536) ? bk[i - 768] : bv[i - 1536];
            bcat[i] = v;
        }
    }
}

// ---------------- MFMA GEMM: out[m][n] = A[m][:]·Bt[n][:] + bias (+resid) --
template<int OUTMODE>
__global__ __launch_bounds__(256)
void gemm_mfma(const ushort* __restrict__ A, const ushort* __restrict__ Bt,
               const float* __restrict__ bias, const float* __restrict__ resid,
               void* __restrict__ outp, ushort* __restrict__ vtp,
               int M, int N, int K, int nscale, float sfac)
{
    __shared__ ushort As[128 * 32];
    __shared__ ushort Bs[128 * 32];
    const int bn = blockIdx.x * 128;
    const int bm = blockIdx.y * 128;
    const int t  = threadIdx.x;
    const int w  = t >> 6, l = t & 63;
    const int lg = l >> 4, lr = l & 15;
    const int wr = w >> 1, wc = w & 1;

    f32x4 acc[4][4];
    #pragma unroll
    for (int i = 0; i < 4; ++i)
        #pragma unroll
        for (int j = 0; j < 4; ++j) acc[i][j] = (f32x4){0.f, 0.f, 0.f, 0.f};

    for (int k0 = 0; k0 < K; k0 += 32) {
        #pragma unroll
        for (int it = 0; it < 2; ++it) {
            const int g = it * 256 + t;
            const int r = g >> 2, cb = (g & 3) * 8;
            GLDS16(A  + (size_t)(bm + r) * K + k0 + cb, (char*)As + g * 16);
            GLDS16(Bt + (size_t)(bn + r) * K + k0 + cb, (char*)Bs + g * 16);
        }
        __syncthreads();
        bf16x8 af[4], bfr[4];
        #pragma unroll
        for (int m16 = 0; m16 < 4; ++m16)
            af[m16] = *(const bf16x8*)&As[(wr * 64 + m16 * 16 + lr) * 32 + lg * 8];
        #pragma unroll
        for (int n16 = 0; n16 < 4; ++n16)
            bfr[n16] = *(const bf16x8*)&Bs[(wc * 64 + n16 * 16 + lr) * 32 + lg * 8];
        #pragma unroll
        for (int m16 = 0; m16 < 4; ++m16)
            #pragma unroll
            for (int n16 = 0; n16 < 4; ++n16)
                acc[m16][n16] = __builtin_amdgcn_mfma_f32_16x16x32_bf16(
                    af[m16], bfr[n16], acc[m16][n16], 0, 0, 0);
        __syncthreads();
    }

    #pragma unroll
    for (int m16 = 0; m16 < 4; ++m16) {
        #pragma unroll
        for (int n16 = 0; n16 < 4; ++n16) {
            const int col = bn + wc * 64 + n16 * 16 + lr;
            const float bcol = bias[col];
            const int row0 = bm + wr * 64 + m16 * 16 + lg * 4;
            float vv[4];
            #pragma unroll
            for (int r = 0; r < 4; ++r) {
                float v = acc[m16][n16][r] + bcol;
                if (OUTMODE == 1) v += resid[(size_t)(row0 + r) * N + col];
                else if (col < nscale) v *= sfac;
                vv[r] = v;
            }
            if (OUTMODE == 1) {
                #pragma unroll
                for (int r = 0; r < 4; ++r)
                    ((float*)outp)[(size_t)(row0 + r) * N + col] = vv[r];
            } else if (col >= 1536) {
                const int dfull = col - 1536;
                const int hh = dfull >> 6, dd = dfull & 63;
                const int bb = row0 >> 11, ss = row0 & 2047;
                ushort4 pk;
                pk.x = f2bf(vv[0]); pk.y = f2bf(vv[1]);
                pk.z = f2bf(vv[2]); pk.w = f2bf(vv[3]);
                *(ushort4*)(vtp + ((size_t)(bb * NHEAD + hh) * HDIM + dd) * S_LEN + ss) = pk;
            } else {
                #pragma unroll
                for (int r = 0; r < 4; ++r)
                    ((ushort*)outp)[(size_t)(row0 + r) * N + col] = f2bf(vv[r]);
            }
        }
    }
}

// ---------------- MFMA flash attention: swapped-QK 32x32, sigma-staged K ---
// kmarg is stored TWICE with a 16B+128B skew so the hi=0/hi=1 half-wave
// broadcast addresses land on disjoint banks (were same-bank 2-address).
// P-packing uses v_cvt_pk_bf16_f32 (1 inst / 2 values).
#define KT     64
#define ATT_QT 128
#define KVHALF (S_LEN / 2)
#define NTILES (KVHALF / KT)   // 16
#define KMSTR  (KVHALF + 4)    // second-copy offset (floats)

__global__ __launch_bounds__(256, 3)
void attn_mfma(const ushort* __restrict__ Qbf, const ushort* __restrict__ Kbf,
               const ushort* __restrict__ Vt, const float* __restrict__ mask,
               ushort* __restrict__ Pp, float* __restrict__ lp)
{
    // XCD chunking: HW round-robins flat id % 8; give each XCD 96 consecutive
    // works = 6 full (h,b,half) combos (all 16 qt together).
    const int flat = blockIdx.x;
    const int wk   = (flat & 7) * 96 + (flat >> 3);
    const int qt   = wk & 15;
    const int c_   = wk >> 4;            // 0..47 = bz*12 + h
    const int h    = c_ % 12;
    const int bz   = c_ / 12;
    const int b    = bz >> 1, half = bz & 1;

    const int t  = threadIdx.x;
    const int w  = t >> 6, l = t & 63;
    const int l31 = l & 31, hi = l >> 5;
    const int q0 = qt * ATT_QT;
    const int kb0 = half * KVHALF;

    __shared__ ushort Ks[3][KT][64];     // 24 KB, swizzled, sigma-row-permuted
    __shared__ ushort Vs[2][HDIM][64];   // 16 KB, swizzled ([d][kv])
    __shared__ float  kmarg[2 * KMSTR];  // 8.2 KB: dup per hi, bank-skewed

    {   // stage kv-mask args once, two bank-skewed copies
        const int i = t * 4;
        f32x4 v = *(const f32x4*)(mask + b * S_LEN + kb0 + i);
        f32x4 o;
        #pragma unroll
        for (int j = 0; j < 4; ++j)
            o[j] = (v[j] >= 0.f) ? 0.f : -1e30f;
        *(f32x4*)&kmarg[i] = o;
        *(f32x4*)&kmarg[KMSTR + i] = o;
    }

    const bool qnL = (mask[b * S_LEN + q0 + w * 32 + l31] < 0.f);

    // Q B-fragments: qa[k] = Q[q=l31][d = 16k + 8hi + j] (pre-scaled by SM_C)
    bf16x8 qa[4];
    {
        const ushort* qsrc = Qbf + (size_t)(b * S_LEN + q0 + w * 32 + l31) * NQKV
                           + h * HDIM + 8 * hi;
        #pragma unroll
        for (int k = 0; k < 4; ++k)
            qa[k] = *(const bf16x8*)(qsrc + 16 * k);
    }

    // staging geometry (T2 swizzle: source column pre-swizzled, LDS linear)
    const int u    = l >> 3;                    // 0..7
    const int scol = ((l & 7) ^ u) * 8;
    // sigma: LDS rows {w*16+u, w*16+u+8} take K rows {srcK, srcK+4}
    const int srcK = w * 16 + u + ((u & 4) ? 4 : 0);
    const int srow = w * 16 + u;                // V rows unpermuted
    const ushort* kLane = Kbf + (size_t)(b * S_LEN + kb0 + srcK) * NQKV
                        + h * HDIM + scol;
    const ushort* vLane = Vt + ((size_t)(b * NHEAD + h) * HDIM + srow) * S_LEN
                        + kb0 + scol;
    char* ldsK = (char*)Ks + w * 2048 + l * 16;
    char* ldsV = (char*)Vs + w * 2048 + l * 16;

    __syncthreads();   // kmarg visible; vmem fully drained

    // prologue: K(0), V(0), K(1)
    GLDS16(kLane, ldsK);
    GLDS16(kLane + (size_t)4 * NQKV, ldsK + 1024);
    GLDS16(vLane, ldsV);
    GLDS16(vLane + (size_t)8 * S_LEN, ldsV + 1024);
    GLDS16(kLane + (size_t)KT * NQKV, ldsK + 8192);
    GLDS16(kLane + (size_t)(KT + 4) * NQKV, ldsK + 8192 + 1024);

    float l_part = 0.f;
    f32x16 accO[2];
    #pragma unroll
    for (int dt = 0; dt < 2; ++dt)
        #pragma unroll
        for (int i = 0; i < 16; ++i) accO[dt][i] = 0.f;

    const int swzl = (l31 & 7) << 4;
    const float* kmBase = &kmarg[hi * KMSTR];

    for (int tt = 0; tt < NTILES; ++tt) {
        if (tt < NTILES - 1) {
            asm volatile("s_waitcnt vmcnt(2)" ::: "memory");
        } else {
            asm volatile("s_waitcnt vmcnt(0)" ::: "memory");
        }
        __builtin_amdgcn_s_barrier();

        if (tt + 1 < NTILES) {
            const ushort* vsrc = vLane + (size_t)(tt + 1) * KT;
            char* lv = ldsV + ((tt + 1) & 1) * 8192;
            GLDS16(vsrc, lv);
            GLDS16(vsrc + (size_t)8 * S_LEN, lv + 1024);
            if (tt + 2 < NTILES) {
                const ushort* ksrc = kLane + (size_t)(tt + 2) * KT * NQKV;
                char* lk = ldsK + ((tt + 2) % 3) * 8192;
                GLDS16(ksrc, lk);
                GLDS16(ksrc + (size_t)4 * NQKV, lk + 1024);
            }
        }

        const char* Kc = (const char*)Ks + (tt % 3) * 8192;
        const char* Vc = (const char*)Vs + (tt & 1) * 8192;

        #pragma unroll
        for (int kvt = 0; kvt < 2; ++kvt) {
            // ---- S^T = K · Q^T (sigma-permuted LDS rows; scale in Q) ----
            f32x16 sc;
            __builtin_amdgcn_s_setprio(1);
            {
                const char* abase = Kc + (kvt * 32 + l31) * 128;
                bf16x8 a0 = *(const bf16x8*)(abase + ((16 * hi +  0) ^ swzl));
                bf16x8 a1 = *(const bf16x8*)(abase + ((16 * hi + 32) ^ swzl));
                bf16x8 a2 = *(const bf16x8*)(abase + ((16 * hi + 64) ^ swzl));
                bf16x8 a3 = *(const bf16x8*)(abase + ((16 * hi + 96) ^ swzl));
                f32x16 z;
                #pragma unroll
                for (int i = 0; i < 16; ++i) z[i] = 0.f;
                sc = __builtin_amdgcn_mfma_f32_32x32x16_bf16(a0, qa[0], z, 0, 0, 0);
                sc = __builtin_amdgcn_mfma_f32_32x32x16_bf16(a1, qa[1], sc, 0, 0, 0);
                sc = __builtin_amdgcn_mfma_f32_32x32x16_bf16(a2, qa[2], sc, 0, 0, 0);
                sc = __builtin_amdgcn_mfma_f32_32x32x16_bf16(a3, qa[3], sc, 0, 0, 0);
            }
            __builtin_amdgcn_s_setprio(0);

            // ---- lane-local softmax: reg q4*4+r <-> logical kv =
            //      16*(q4>>1) + 8*hi + 4*(q4&1) + r  (sigma mapping) ----
            float p[16];
            const float* km = kmBase + tt * 64 + kvt * 32;
            #pragma unroll
            for (int q4 = 0; q4 < 4; ++q4) {
                const int kvb = 16 * (q4 >> 1) + 8 * hi + 4 * (q4 & 1);
                f32x4 kq = *(const f32x4*)(km + kvb);
                #pragma unroll
                for (int r = 0; r < 4; ++r) {
                    float arg = sc[q4 * 4 + r] + kq[r];
                    arg = qnL ? 0.f : arg;
                    const float pv = exp2f(arg);
                    p[q4 * 4 + r] = pv;
                    l_part += pv;
                }
            }

            // ---- PV: A-frag = p[0..7]/p[8..15] in order; B-frag = b128 ----
            __builtin_amdgcn_s_setprio(1);
            #pragma unroll
            for (int cc = 0; cc < 2; ++cc) {
                i32x4 pku;
                pku[0] = (int)cvt_pk_bf16(p[8 * cc + 0], p[8 * cc + 1]);
                pku[1] = (int)cvt_pk_bf16(p[8 * cc + 2], p[8 * cc + 3]);
                pku[2] = (int)cvt_pk_bf16(p[8 * cc + 4], p[8 * cc + 5]);
                pku[3] = (int)cvt_pk_bf16(p[8 * cc + 6], p[8 * cc + 7]);
                bf16x8 pa;
                __builtin_memcpy(&pa, &pku, 16);
                const int c = kvt * 2 + cc;   // kv chunk of 16 within tile
                #pragma unroll
                for (int dt = 0; dt < 2; ++dt) {
                    bf16x8 bv = *(const bf16x8*)(Vc + (32 * dt + l31) * 128
                                                 + ((32 * c + 16 * hi) ^ swzl));
                    accO[dt] = __builtin_amdgcn_mfma_f32_32x32x16_bf16(
                        pa, bv, accO[dt], 0, 0, 0);
                }
            }
            __builtin_amdgcn_s_setprio(0);
        }
    }

    // full denominator for q = l31: sum the two lane-halves
    l_part += __shfl_xor(l_part, 32, 64);

    // write unnormalized partial O (bf16) + l (f32)
    const size_t MN = (size_t)M_TOT * H_DIM;
    #pragma unroll
    for (int dt = 0; dt < 2; ++dt) {
        #pragma unroll
        for (int reg = 0; reg < 16; ++reg) {
            const int q = (reg & 3) + 8 * (reg >> 2) + 4 * hi;
            const int m = b * S_LEN + q0 + w * 32 + q;
            Pp[(size_t)half * MN + (size_t)m * H_DIM + h * HDIM + 32 * dt + l31]
                = f2bf(accO[dt][reg]);
        }
    }
    if (hi == 0) {
        const int m = b * S_LEN + q0 + w * 32 + l31;
        lp[half * (M_TOT * NHEAD) + m * NHEAD + h] = l_part;
    }
}

// ---------------- combine: ctx = (P0+P1)/(l0+l1) ---------------------------
__global__ __launch_bounds__(256)
void combine_kernel(const ushort* __restrict__ Pp, const float* __restrict__ lp,
                    ushort* __restrict__ ctx)
{
    const int idx = blockIdx.x * 256 + threadIdx.x;   // over M_TOT*96
    const int m  = idx / 96;
    const int c8 = idx % 96;
    const int c  = c8 * 8;
    const int h  = c8 >> 3;
    const size_t MN = (size_t)M_TOT * H_DIM;

    const float lsum = lp[m * NHEAD + h] + lp[M_TOT * NHEAD + m * NHEAD + h];
    const float inv  = 1.0f / lsum;

    bf16x8 a = *(const bf16x8*)(Pp + (size_t)m * H_DIM + c);
    bf16x8 b = *(const bf16x8*)(Pp + MN + (size_t)m * H_DIM + c);
    bf16x8 o;
    #pragma unroll
    for (int j = 0; j < 8; ++j)
        o[j] = (short)f2bf((bf2f((ushort)a[j]) + bf2f((ushort)b[j])) * inv);
    *(bf16x8*)(ctx + (size_t)m * H_DIM + c) = o;
}

// ---------------- LayerNorm (wave-per-row, shuffle reduce, no LDS) ---------
__global__ __launch_bounds__(256)
void ln_kernel(const float* __restrict__ Hbuf, const float* __restrict__ gamma,
               const float* __restrict__ beta, float* __restrict__ out)
{
    const int m = blockIdx.x * 4 + (threadIdx.x >> 6);
    const int l = threadIdx.x & 63;
    const float* row = Hbuf + (size_t)m * H_DIM;

    f32x4 x[3];
    #pragma unroll
    for (int k = 0; k < 3; ++k) x[k] = *(const f32x4*)(row + l * 4 + k * 256);

    float s = 0.f;
    #pragma unroll
    for (int k = 0; k < 3; ++k)
        #pragma unroll
        for (int j = 0; j < 4; ++j) s += x[k][j];
    #pragma unroll
    for (int off = 1; off < 64; off <<= 1) s += __shfl_xor(s, off, 64);
    const float mu = s * (1.0f / H_DIM);

    float v = 0.f;
    #pragma unroll
    for (int k = 0; k < 3; ++k)
        #pragma unroll
        for (int j = 0; j < 4; ++j) {
            const float d = x[k][j] - mu;
            v += d * d;
        }
    #pragma unroll
    for (int off = 1; off < 64; off <<= 1) v += __shfl_xor(v, off, 64);
    const float rstd = rsqrtf(v * (1.0f / H_DIM) + LN_EPS);

    #pragma unroll
    for (int k = 0; k < 3; ++k) {
        const int c = l * 4 + k * 256;
        f32x4 gm = *(const f32x4*)(gamma + c);
        f32x4 bt = *(const f32x4*)(beta + c);
        f32x4 o;
        #pragma unroll
        for (int j = 0; j < 4; ++j)
            o[j] = (x[k][j] - mu) * rstd * gm[j] + bt[j];
        *(f32x4*)(out + (size_t)m * H_DIM + c) = o;
    }
}

// ---------------------------------------------------------------------------
extern "C" void kernel_launch(void* const* d_in, const int* in_sizes, int n_in,
                              void* d_out, int out_size, void* d_ws, size_t ws_size,
                              hipStream_t stream)
{
    const float* hs   = (const float*)d_in[0];
    const float* mask = (const float*)d_in[1];
    const float* Wq   = (const float*)d_in[2];
    const float* bq   = (const float*)d_in[3];
    const float* Wk   = (const float*)d_in[4];
    const float* bk   = (const float*)d_in[5];
    const float* Wv   = (const float*)d_in[6];
    const float* bv   = (const float*)d_in[7];
    const float* Wo   = (const float*)d_in[8];
    const float* bo   = (const float*)d_in[9];
    const float* g    = (const float*)d_in[10];
    const float* be   = (const float*)d_in[11];
    float* out = (float*)d_out;

    char* base = (char*)d_ws;
    ushort* Xbf    = (ushort*)(base);                    //  6,291,456 B
    ushort* QKVbf  = (ushort*)(base + 6291456);          // 18,874,368 B
    ushort* Wcat   = (ushort*)(base + 25165824);         //  3,538,944 B (lp after QKV gemm)
    ushort* Wot    = (ushort*)(base + 28704768);         //  1,179,648 B
    float*  bcat   = (float*) (base + 29884416);         //      9,216 B
    ushort* Vt     = (ushort*)(base + 29893632);         //  6,291,456 B
    ushort* Cbf    = (ushort*)(base + 36185088);         //  6,291,456 B
    float*  Hb     = (float*) (base + 42476544);         // 12,582,912 B (Pp before out-GEMM)
    float*  lp     = (float*) (base + 25165824);         // reuse Wcat region
    ushort* Pp     = (ushort*)(base + 42476544);         // reuse Hb region

    prep<<<3657, 256, 0, stream>>>(hs, Wq, Wk, Wv, Wo, bq, bk, bv,
                                   Xbf, Wcat, Wot, bcat);

    // Q cols (<768) pre-scaled by SM_C; V cols (>=1536) fused-transposed to Vt
    gemm_mfma<0><<<dim3(NQKV / 128, M_TOT / 128), 256, 0, stream>>>(
        Xbf, Wcat, bcat, nullptr, QKVbf, Vt, M_TOT, NQKV, H_DIM, 768, SM_C);

    attn_mfma<<<768, 256, 0, stream>>>(
        QKVbf, QKVbf + 768, Vt, mask, Pp, lp);

    combine_kernel<<<M_TOT * 96 / 256, 256, 0, stream>>>(Pp, lp, Cbf);

    gemm_mfma<1><<<dim3(H_DIM / 128, M_TOT / 128), 256, 0, stream>>>(
        Cbf, Wot, bo, hs, Hb, nullptr, M_TOT, H_DIM, H_DIM, 0, 1.0f);

    ln_kernel<<<M_TOT / 4, 256, 0, stream>>>(Hb, g, be, out);
}